// Round 15
// baseline (163.280 us; speedup 1.0000x reference)
//
#include <hip/hip_runtime.h>
#include <hip/hip_bf16.h>

__device__ __forceinline__ float sigm(float x) { return 1.f / (1.f + expf(-x)); }
__device__ __forceinline__ float lrelu(float x) { return x > 0.f ? x : 0.2f * x; }
__device__ __forceinline__ float eluf(float x) { return x > 0.f ? x : expf(x) - 1.f; }

#define NEGF (-9e15f)
#define MAXD 40   // deg ~ Binom(4096,1/512): mean 8, sigma 2.8 -> P(deg>40) ~ 1e-28

__device__ __forceinline__ float wave_sum(float v) {
    #pragma unroll
    for (int off = 32; off >= 1; off >>= 1) v += __shfl_xor(v, off);
    return v;
}
__device__ __forceinline__ float wave_max(float v) {
    #pragma unroll
    for (int off = 32; off >= 1; off >>= 1) v = fmaxf(v, __shfl_xor(v, off));
    return v;
}
__device__ __forceinline__ float half_sum(float v) {
    #pragma unroll
    for (int off = 16; off >= 1; off >>= 1) v += __shfl_xor(v, off);
    return v;
}
__device__ __forceinline__ float half_max(float v) {
    #pragma unroll
    for (int off = 16; off >= 1; off >>= 1) v = fmaxf(v, __shfl_xor(v, off));
    return v;
}

// ---------------- K_setup ----------------
// grid 176, block 256 (roles as before)
__global__ void k_setup(const float* __restrict__ Wg, const float* __restrict__ Weg,
                        const float* __restrict__ asrc, const float* __restrict__ adst,
                        const float* __restrict__ aedge, const float* __restrict__ Weo,
                        const float* __restrict__ aoe,
                        const float* __restrict__ feat, const float* __restrict__ Wsn,
                        const float* __restrict__ asn, const float* __restrict__ g1W,
                        const float* __restrict__ g1b,
                        float* __restrict__ vs1, float* __restrict__ vd1, float* __restrict__ ve1,
                        float* __restrict__ ve2, int* __restrict__ winner,
                        float* __restrict__ h, float* __restrict__ gate1) {
    int b = blockIdx.x, t = threadIdx.x, w = t >> 6, l = t & 63;
    __shared__ float fr[4][64];
    if (b < 16) {
        int hd = b;
        float s0 = asrc[hd * 128 + l],  s1 = asrc[hd * 128 + 64 + l];
        float d0 = adst[hd * 128 + l],  d1 = adst[hd * 128 + 64 + l];
        float e0 = aedge[hd * 128 + l], e1 = aedge[hd * 128 + 64 + l];
        for (int i = w; i < 64; i += 4) {
            const float* Wr = Wg  + ((size_t)hd * 64 + i) * 128;
            const float* Er = Weg + ((size_t)hd * 64 + i) * 128;
            float w1 = Wr[l], w2 = Wr[64 + l];
            float q1 = Er[l], q2 = Er[64 + l];
            float pS = wave_sum(w1 * s0 + w2 * s1);
            float pD = wave_sum(w1 * d0 + w2 * d1);
            float pE = wave_sum(q1 * e0 + q2 * e1);
            if (l == 0) { vs1[hd * 64 + i] = pS; vd1[hd * 64 + i] = pD; ve1[hd * 64 + i] = pE; }
        }
    } else if (b < 32) {
        int base = (b - 16) * 128;
        float a0 = aoe[l], a1 = aoe[64 + l];
        for (int k = 0; k < 32; k++) {
            int c = base + w * 32 + k;
            const float* Wr = Weo + (size_t)c * 128;
            float p = wave_sum(Wr[l] * a0 + Wr[64 + l] * a1);
            if (l == 0) ve2[c] = p;
        }
    } else if (b < 48) {
        int base = (b - 32) * 4096;
        #pragma unroll
        for (int k = 0; k < 16; k++) winner[base + k * 256 + t] = -1;
    } else {
        int n = (b - 48) * 4 + w;
        fr[w][l] = feat[n * 64 + l];
        __syncthreads();
        float acc = 0.f;
        #pragma unroll 8
        for (int i = 0; i < 64; i++) acc += fr[w][i] * Wsn[i * 64 + l];
        float p = wave_sum(acc * asn[l]);
        float coef = sigm(lrelu(p));
        float hv = eluf(coef * acc);
        h[n * 64 + l] = hv;
        float g = wave_sum(hv * g1W[l]);
        if (l == 0) gate1[n] = sigm(g + g1b[0]);
    }
}

// ---------------- K_mid: wsum1p (b 0..7) | es1/ed1 (b 8..23) | scatter (b 24..31) ----------------
// grid 32, block 512
__global__ void k_mid(const float* __restrict__ h, const float* __restrict__ gate,
                      const float* __restrict__ vs1, const float* __restrict__ vd1,
                      const int* __restrict__ ei,
                      float* __restrict__ part1, float* __restrict__ es1, float* __restrict__ ed1,
                      int* __restrict__ winner) {
    int b = blockIdx.x, t = threadIdx.x;
    if (b < 8) {
        int nb = b, w = t >> 6, l = t & 63;
        __shared__ float mx[8], sm[8], al[512], pt[8][64];
        float g = gate[t];
        float m = wave_max(g);
        if (l == 0) mx[w] = m;
        __syncthreads();
        m = mx[0];
        #pragma unroll
        for (int i = 1; i < 8; i++) m = fmaxf(m, mx[i]);
        float p = expf(g - m);
        float Z = wave_sum(p);
        if (l == 0) sm[w] = Z;
        __syncthreads();
        Z = 0.f;
        #pragma unroll
        for (int i = 0; i < 8; i++) Z += sm[i];
        al[t] = p / Z;
        __syncthreads();
        int r0 = nb * 64 + w * 8;
        float acc = 0.f;
        #pragma unroll
        for (int r = 0; r < 8; r++) acc += al[r0 + r] * h[(r0 + r) * 64 + l];
        pt[w][l] = acc;
        __syncthreads();
        if (t < 64) {
            float o = 0.f;
            #pragma unroll
            for (int q = 0; q < 8; q++) o += pt[q][t];
            part1[nb * 64 + t] = o;
        }
    } else if (b < 24) {
        __shared__ float vsT[64][17], vdT[64][17];
        for (int idx = t; idx < 1024; idx += 512) {
            int i = idx & 63, hd = idx >> 6;
            vsT[i][hd] = vs1[hd * 64 + i];
            vdT[i][hd] = vd1[hd * 64 + i];
        }
        __syncthreads();
        int idx = (b - 8) * 512 + t;
        int n = idx >> 4, hd = idx & 15;
        const float* hr = h + n * 64;
        float aS = 0.f, aD = 0.f;
        #pragma unroll 8
        for (int i = 0; i < 64; i++) {
            float hv = hr[i];
            aS += hv * vsT[i][hd];
            aD += hv * vdT[i][hd];
        }
        es1[hd * 512 + n] = aS;
        ed1[hd * 512 + n] = aD;
    } else {
        int e = (b - 24) * 512 + t;
        int s = ei[e] >> 1, d = ei[4096 + e] >> 1;
        atomicMax(&winner[s * 256 + d], e);
    }
}

// ---------------- K_attn_ze: attn_z (b 0..511) | edot-partial (b 512..767) ----------------
// grid 768, block 512. LDS union: max(attn 33.6KB, edot 34.8KB)
__global__ void k_attn_ze(const float* __restrict__ adj, const float* __restrict__ n2n,
                          const float* __restrict__ h, const float* __restrict__ ve1,
                          const float* __restrict__ es1, const float* __restrict__ ed1,
                          const float* __restrict__ eattr, const float* __restrict__ Weg,
                          const float* __restrict__ ve2,
                          float* __restrict__ z, float* __restrict__ d2p) {
    int b = blockIdx.x, t = threadIdx.x, w = t >> 6, l = t & 63;
    __shared__ __align__(16) char smem[34816];
    if (b >= 512) {
        // block = (head hd, 256-edge chunk); Weg[hd] staged in LDS (32KB);
        // wave w computes edge e0+ebase+w; lane l covers channels l and 64+l.
        float (*Wl)[128] = reinterpret_cast<float(*)[128]>(smem);
        float (*ea8)[64] = reinterpret_cast<float(*)[64]>(smem + 32768);
        int bb = b - 512;
        int hd = bb & 15, e0 = (bb >> 4) * 256;
        for (int idx = t; idx < 8192; idx += 512)
            Wl[idx >> 7][idx & 127] = Weg[(size_t)hd * 8192 + idx];
        float v2a = ve2[hd * 128 + l];
        float v2b = ve2[hd * 128 + 64 + l];
        for (int ebase = 0; ebase < 256; ebase += 8) {
            __syncthreads();
            ea8[t >> 6][t & 63] = eattr[(size_t)(e0 + ebase + (t >> 6)) * 64 + (t & 63)];
            __syncthreads();
            float a0 = 0.f, a1 = 0.f;
            #pragma unroll 8
            for (int i = 0; i < 64; i++) {
                float r = ea8[w][i];
                a0 += r * Wl[i][l];
                a1 += r * Wl[i][64 + l];
            }
            float p = eluf(a0) * v2a + eluf(a1) * v2b;
            p = wave_sum(p);
            if (l == 0) d2p[hd * 4096 + e0 + ebase + w] = p;
        }
        return;
    }
    int s = b;
    float (*vlT)[17]  = reinterpret_cast<float(*)[17]>(smem);          // 4352
    float (*hrow)[65] = reinterpret_cast<float(*)[65]>(smem + 4352);   // 10400
    float (*nrow)[65] = reinterpret_cast<float(*)[65]>(smem + 14752);  // 10400
    float (*eh)[48]   = reinterpret_cast<float(*)[48]>(smem + 25152);  // 3072
    float (*ah)[48]   = reinterpret_cast<float(*)[48]>(smem + 28224);  // 3072
    float *esr        = reinterpret_cast<float*>(smem + 31296);        // 64
    int   *dlist      = reinterpret_cast<int*>(smem + 31360);          // 160
    int   *wbase      = reinterpret_cast<int*>(smem + 31520);          // 32
    int   *nnz_sp     = reinterpret_cast<int*>(smem + 31552);          // 4
    float (*part)[64] = reinterpret_cast<float(*)[64]>(smem + 31568);  // 2048

    for (int idx = t; idx < 1024; idx += 512) vlT[idx & 63][idx >> 6] = ve1[(idx >> 6) * 64 + (idx & 63)];
    if (t < 16) esr[t] = es1[t * 512 + s];
    float a = adj[s * 512 + t];
    unsigned long long mask = __ballot(a > 0.f);
    if (l == 0) wbase[w] = __popcll(mask);
    __syncthreads();
    if (t == 0) {
        int run = 0;
        #pragma unroll
        for (int i = 0; i < 8; i++) { int c = wbase[i]; wbase[i] = run; run += c; }
        nnz_sp[0] = run;
    }
    __syncthreads();
    if (a > 0.f) {
        int slot = wbase[w] + __popcll(mask & ((1ULL << l) - 1ULL));
        if (slot < MAXD) dlist[slot] = t;
    }
    __syncthreads();
    int nnz = min(nnz_sp[0], MAXD);

    if (nnz == 0) {
        int i = t & 63, q = t >> 6;
        float acc = 0.f;
        for (int d = q * 64; d < q * 64 + 64; d++) acc += h[d * 64 + i];
        part[q][i] = acc;
        __syncthreads();
        if (t < 64) {
            float sum = 0.f;
            #pragma unroll
            for (int q2 = 0; q2 < 8; q2++) sum += part[q2][t];
            float v = sum * (1.f / 512.f);
            for (int hd = 0; hd < 16; hd++) z[(size_t)s * 1024 + hd * 64 + t] = v;
        }
        return;
    }

    for (int base = 0; base < nnz; base += 8) {
        int j = base + (t >> 6);
        if (j < nnz) {
            int d = dlist[j];
            hrow[j][l] = h[d * 64 + l];
            nrow[j][l] = n2n[((size_t)s * 512 + d) * 64 + l];
        }
    }
    __syncthreads();
    for (int jb = 0; jb < nnz; jb += 32) {
        int j = jb + (t >> 4), hd = t & 15;
        if (j < nnz) {
            float ee = 0.f;
            #pragma unroll 8
            for (int i = 0; i < 64; i++) ee += nrow[j][i] * vlT[i][hd];
            eh[hd][j] = lrelu(esr[hd] + ed1[hd * 512 + dlist[j]] + ee);
        }
    }
    __syncthreads();
    {
        int hd = t >> 5, lane32 = t & 31;
        float v0 = (lane32 < nnz) ? eh[hd][lane32] : -1e30f;
        float v1 = (lane32 + 32 < nnz) ? eh[hd][lane32 + 32] : -1e30f;
        float m = half_max(fmaxf(v0, v1));
        float p0 = (lane32 < nnz) ? expf(v0 - m) : 0.f;
        float p1 = (lane32 + 32 < nnz) ? expf(v1 - m) : 0.f;
        float Z = half_sum(p0 + p1);
        float inv = 1.f / Z;
        if (lane32 < nnz) ah[hd][lane32] = p0 * inv;
        if (lane32 + 32 < nnz) ah[hd][lane32 + 32] = p1 * inv;
    }
    __syncthreads();
    int hd = t >> 5, i0 = t & 31;
    float a0 = 0.f, a1 = 0.f;
    for (int j = 0; j < nnz; j++) {
        float aj = ah[hd][j];
        a0 += aj * hrow[j][i0];
        a1 += aj * hrow[j][i0 + 32];
    }
    z[(size_t)s * 1024 + hd * 64 + i0]      = a0;
    z[(size_t)s * 1024 + hd * 64 + i0 + 32] = a1;
}

// ---------------- K_houtg: hout = elu(z@Wg) | d2 reduce (blockIdx.y==16) ----------------
// grid (64, 17), block 128
__global__ void k_houtg(const float* __restrict__ z, const float* __restrict__ Wg,
                        const float* __restrict__ d2p,
                        float* __restrict__ hout, float* __restrict__ d2) {
    int sb = blockIdx.x, hd = blockIdx.y, c = threadIdx.x;
    if (hd == 16) {
        if (c < 64) {
            int e = sb * 64 + c;
            float s = 0.f;
            #pragma unroll
            for (int k = 0; k < 16; k++) s += d2p[k * 4096 + e];
            d2[e] = s;
        }
        return;
    }
    __shared__ float zt[8][64];
    int s0 = sb * 8;
    for (int idx = c; idx < 512; idx += 128) {
        int r = idx >> 6, i = idx & 63;
        zt[r][i] = z[(size_t)(s0 + r) * 1024 + hd * 64 + i];
    }
    __syncthreads();
    float acc[8] = {0, 0, 0, 0, 0, 0, 0, 0};
    const float* W = Wg + (size_t)hd * 8192 + c;
    #pragma unroll 8
    for (int i = 0; i < 64; i++) {
        float wv = W[(size_t)i * 128];
        #pragma unroll
        for (int r = 0; r < 8; r++) acc[r] += zt[r][i] * wv;
    }
    #pragma unroll
    for (int r = 0; r < 8; r++)
        hout[(size_t)(s0 + r) * 2048 + hd * 128 + c] = eluf(acc[r]);
}

// ---------------- K_big2p: pool1 + gate2 + wh2 fused (2 x1p rows / block) ----------------
// grid 128, block 1024; stages hout1 rows 4b..4b+3, pools in LDS, GEMM from LDS
__global__ void k_big2p(const float* __restrict__ hout1, const float* __restrict__ Wp1,
                        const float* __restrict__ bp1, const float* __restrict__ g2W,
                        const float* __restrict__ g2b, const float* __restrict__ Wo,
                        const float* __restrict__ aos, const float* __restrict__ aod,
                        float* __restrict__ x1p, float* __restrict__ gate2,
                        float* __restrict__ Wh2, float* __restrict__ es2, float* __restrict__ ed2) {
    int b = blockIdx.x, t = threadIdx.x;
    __shared__ float hs[4][2048];       // 32KB
    __shared__ float xr[2][2048];       // 16KB
    __shared__ float part[8][2][128];   // 8KB
    __shared__ float red[16], rs[4], rd[4];
    int n0 = 2 * b;
    for (int idx = t; idx < 8192; idx += 1024)
        hs[idx >> 11][idx & 2047] = hout1[(size_t)(4 * b) * 2048 + idx];
    __syncthreads();
    int g = t >> 9, tt = t & 511;       // 2 pool-pairs, 512 thr each
    float p = 0.f;
    for (int f = tt; f < 2048; f += 512)
        p += hs[2 * g][f] * Wp1[f] + hs[2 * g + 1][f] * Wp1[2048 + f];
    p = wave_sum(p);
    if ((t & 63) == 0) red[t >> 6] = p;
    __syncthreads();
    float s8 = 0.f;
    #pragma unroll
    for (int k2 = 0; k2 < 8; k2++) s8 += red[g * 8 + k2];
    float sc = sigm(s8 + bp1[0]);
    __syncthreads();                     // red reads done before reuse
    float pg = 0.f;
    for (int f = tt; f < 2048; f += 512) {
        float v = (hs[2 * g][f] + hs[2 * g + 1][f]) * sc;
        xr[g][f] = v;
        x1p[(size_t)(n0 + g) * 2048 + f] = v;
        pg += v * g2W[f];
    }
    pg = wave_sum(pg);
    if ((t & 63) == 0) red[t >> 6] = pg;
    __syncthreads();                     // xr complete + red(pg) complete
    if (t == 0 || t == 512) {
        float sg8 = 0.f;
        #pragma unroll
        for (int k2 = 0; k2 < 8; k2++) sg8 += red[g * 8 + k2];
        gate2[n0 + g] = sigm(sg8 + g2b[0]);
    }
    // wh2 GEMM from LDS xr
    int ks = t >> 7, c = t & 127;
    float a0 = 0.f, a1 = 0.f;
    const float* W  = Wo + (size_t)(ks * 256) * 128 + c;
    const float* x0 = xr[0] + ks * 256;
    const float* x1 = xr[1] + ks * 256;
    #pragma unroll 8
    for (int i = 0; i < 256; i++) { float w = W[(size_t)i * 128]; a0 += x0[i] * w; a1 += x1[i] * w; }
    part[ks][0][c] = a0;
    part[ks][1][c] = a1;
    __syncthreads();
    if (t < 256) {
        int r = t >> 7, cc = t & 127;
        float a = 0.f;
        #pragma unroll
        for (int k2 = 0; k2 < 8; k2++) a += part[k2][r][cc];
        Wh2[(n0 + r) * 128 + cc] = a;
        float ps = wave_sum(a * aos[cc]);
        float pd = wave_sum(a * aod[cc]);
        if ((t & 63) == 0) { rs[t >> 6] = ps; rd[t >> 6] = pd; }
    }
    __syncthreads();
    if (t == 0) { es2[n0] = rs[0] + rs[1]; ed2[n0] = rd[0] + rd[1]; }
    if (t == 1) { es2[n0 + 1] = rs[2] + rs[3]; ed2[n0 + 1] = rd[2] + rd[3]; }
}

// ---------------- K_fin: attn2 (b 0..255) | wsum2p (b 256..319) ----------------
// grid 320, block 256
__global__ void k_fin(const int* __restrict__ winner, const float* __restrict__ d2,
                      const float* __restrict__ es2, const float* __restrict__ ed2,
                      const float* __restrict__ Wh2, const float* __restrict__ gate2,
                      const float* __restrict__ x1p,
                      float* __restrict__ part2, float* __restrict__ hout2) {
    int b = blockIdx.x, t = threadIdx.x;
    if (b < 256) {
        int s = b, w = t >> 6, l = t & 63;
        __shared__ float mx[4], sm[4], at[256], part[2][128];
        int win = winner[s * 256 + t];
        float e;
        if (win >= 0) e = lrelu(es2[s] + ed2[t] + d2[win]);
        else e = NEGF;
        float m = wave_max(e);
        if (l == 0) mx[w] = m;
        __syncthreads();
        m = fmaxf(fmaxf(mx[0], mx[1]), fmaxf(mx[2], mx[3]));
        float p = expf(e - m);
        float Z = wave_sum(p);
        if (l == 0) sm[w] = Z;
        __syncthreads();
        Z = sm[0] + sm[1] + sm[2] + sm[3];
        at[t] = p / Z;
        __syncthreads();
        int c = t & 127, hf = t >> 7;
        float acc = 0.f;
        for (int d = hf * 128; d < hf * 128 + 128; d++)
            acc += at[d] * Wh2[d * 128 + c];
        part[hf][c] = acc;
        __syncthreads();
        if (t < 128) hout2[s * 128 + t] = part[0][t] + part[1][t];   // concat=False: no elu
    } else {
        int tile = b - 256;              // 0..63
        int cb = tile >> 3, nb = tile & 7;
        __shared__ float mx2[4], sm2[4], al[256];
        int w = t >> 6, l = t & 63;
        float g = gate2[t];
        float m = wave_max(g);
        if (l == 0) mx2[w] = m;
        __syncthreads();
        m = fmaxf(fmaxf(mx2[0], mx2[1]), fmaxf(mx2[2], mx2[3]));
        float p = expf(g - m);
        float Z = wave_sum(p);
        if (l == 0) sm2[w] = Z;
        __syncthreads();
        Z = sm2[0] + sm2[1] + sm2[2] + sm2[3];
        al[t] = p / Z;
        __syncthreads();
        int c = cb * 256 + t;
        int n0 = nb * 32;
        float acc = 0.f;
        #pragma unroll 8
        for (int n = n0; n < n0 + 32; n++) acc += al[n] * x1p[(size_t)n * 2048 + c];
        part2[nb * 2048 + c] = acc;
    }
}

// ---------------- K_tail: pool2+gate3+gattn3 (b 0) | wsumr (b 1..9) ----------------
// grid 10, block 512
__global__ void k_tail(const float* __restrict__ hout2, const float* __restrict__ Wp,
                       const float* __restrict__ bp, const float* __restrict__ g3W,
                       const float* __restrict__ g3b, const float* __restrict__ part1,
                       const float* __restrict__ part2, float* __restrict__ out) {
    int t = threadIdx.x, w = t >> 6, l = t & 63;
    if (blockIdx.x > 0) {
        int rb = blockIdx.x - 1;
        if (rb == 0) {
            if (t < 64) {
                float o = 0.f;
                #pragma unroll
                for (int nb = 0; nb < 8; nb++) o += part1[nb * 64 + t];
                out[t] = o;
            }
        } else if (t < 256) {
            int c = (rb - 1) * 256 + t;
            float o = 0.f;
            #pragma unroll
            for (int nb = 0; nb < 8; nb++) o += part2[nb * 2048 + c];
            out[64 + c] = o;
        }
        return;
    }
    __shared__ float x2s[128][129];
    __shared__ float gt[128];
    __shared__ float mx[2], sm[2], al[128], part[4][128];
    float bpv = bp[0], g3bv = g3b[0];
    for (int rr = 0; rr < 16; rr++) {
        int k = w * 16 + rr;
        float a0  = hout2[(size_t)(2 * k) * 128 + l];
        float a0b = hout2[(size_t)(2 * k) * 128 + 64 + l];
        float a1  = hout2[(size_t)(2 * k + 1) * 128 + l];
        float a1b = hout2[(size_t)(2 * k + 1) * 128 + 64 + l];
        float p = a0 * Wp[l] + a0b * Wp[64 + l] + a1 * Wp[128 + l] + a1b * Wp[192 + l];
        p = wave_sum(p);
        float sc = sigm(p + bpv);
        float v  = (a0 + a1) * sc;
        float vb = (a0b + a1b) * sc;
        x2s[k][l] = v;
        x2s[k][64 + l] = vb;
        float g = wave_sum(v * g3W[l] + vb * g3W[64 + l]);
        if (l == 0) gt[k] = sigm(g + g3bv);
    }
    __syncthreads();
    if (t < 128) {
        float g = gt[t];
        float m = wave_max(g);
        if (l == 0) mx[w] = m;
    }
    __syncthreads();
    if (t < 128) {
        float g = gt[t];
        float m = fmaxf(mx[0], mx[1]);
        float p = expf(g - m);
        float Z = wave_sum(p);
        if (l == 0) sm[w] = Z;
        al[t] = p;
    }
    __syncthreads();
    float invZ = 1.f / (sm[0] + sm[1]);
    int q = t >> 7, c = t & 127;
    float acc = 0.f;
    for (int n = q * 32; n < q * 32 + 32; n++) acc += al[n] * x2s[n][c];
    part[q][c] = acc * invZ;
    __syncthreads();
    if (t < 128) out[2112 + t] = part[0][t] + part[1][t] + part[2][t] + part[3][t];
}

extern "C" void kernel_launch(void* const* d_in, const int* in_sizes, int n_in,
                              void* d_out, int out_size, void* d_ws, size_t ws_size,
                              hipStream_t stream) {
    const float* feat  = (const float*)d_in[0];
    const int*   eidx  = (const int*)d_in[1];
    const float* eattr = (const float*)d_in[2];
    const float* adj   = (const float*)d_in[3];
    const float* n2n   = (const float*)d_in[4];
    const float* Wsn   = (const float*)d_in[5];
    const float* asn   = (const float*)d_in[6];
    const float* Wg    = (const float*)d_in[7];
    const float* Weg   = (const float*)d_in[8];
    const float* asrc  = (const float*)d_in[9];
    const float* adst  = (const float*)d_in[10];
    const float* aedge = (const float*)d_in[11];
    const float* Wp1   = (const float*)d_in[12];
    const float* bp1   = (const float*)d_in[13];
    const float* Wo    = (const float*)d_in[14];
    const float* Weo   = (const float*)d_in[15];
    const float* aos   = (const float*)d_in[16];
    const float* aod   = (const float*)d_in[17];
    const float* aoe   = (const float*)d_in[18];
    const float* Wp2   = (const float*)d_in[19];
    const float* bp2   = (const float*)d_in[20];
    const float* g1W   = (const float*)d_in[21];
    const float* g1b   = (const float*)d_in[22];
    const float* g2W   = (const float*)d_in[23];
    const float* g2b   = (const float*)d_in[24];
    const float* g3W   = (const float*)d_in[25];
    const float* g3b   = (const float*)d_in[26];
    float* out = (float*)d_out;

    char* ws = (char*)d_ws;
    float* h      = (float*)(ws + 0x0000000);   // 128KB
    float* z      = (float*)(ws + 0x0020000);   // 2MB
    float* ve1    = (float*)(ws + 0x0430000);   // 4KB
    float* ve2    = (float*)(ws + 0x0431000);   // 8KB
    float* gate1  = (float*)(ws + 0x0433000);   // 2KB
    float* gate2  = (float*)(ws + 0x0434000);   // 1KB
    float* vs1    = (float*)(ws + 0x0436000);   // 4KB
    float* vd1    = (float*)(ws + 0x0438000);   // 4KB
    float* es1    = (float*)(ws + 0x0440000);   // 32KB
    float* ed1    = (float*)(ws + 0x0448000);   // 32KB
    float* d2p    = (float*)(ws + 0x0500000);   // 16*4096*4 = 256KB
    float* hout1  = (float*)(ws + 0x1440000);   // 4MB
    float* d2     = (float*)(ws + 0x1840000);   // 16KB
    float* x1p    = (float*)(ws + 0x1850000);   // 2MB
    int*   winner = (int*)  (ws + 0x1A50000);   // 256KB
    float* Wh2    = (float*)(ws + 0x1A90000);   // 128KB
    float* es2    = (float*)(ws + 0x1AB0000);   // 1KB
    float* ed2    = (float*)(ws + 0x1AB1000);   // 1KB
    float* hout2  = (float*)(ws + 0x1AB2000);   // 128KB
    float* part2  = (float*)(ws + 0x1AE2000);   // 64KB
    float* part1  = (float*)(ws + 0x1AF2000);   // 2KB

    k_setup  <<<176, 256, 0, stream>>>(Wg, Weg, asrc, adst, aedge, Weo, aoe,
                                       feat, Wsn, asn, g1W, g1b,
                                       vs1, vd1, ve1, ve2, winner, h, gate1);
    k_mid    <<<32, 512, 0, stream>>>(h, gate1, vs1, vd1, eidx, part1, es1, ed1, winner);
    k_attn_ze<<<768, 512, 0, stream>>>(adj, n2n, h, ve1, es1, ed1, eattr, Weg, ve2, z, d2p);
    k_houtg  <<<dim3(64, 17), 128, 0, stream>>>(z, Wg, d2p, hout1, d2);
    k_big2p  <<<128, 1024, 0, stream>>>(hout1, Wp1, bp1, g2W, g2b, Wo, aos, aod,
                                        x1p, gate2, Wh2, es2, ed2);
    k_fin    <<<320, 256, 0, stream>>>(winner, d2, es2, ed2, Wh2, gate2, x1p, part2, hout2);
    k_tail   <<<10, 512, 0, stream>>>(hout2, Wp2, bp2, g3W, g3b, part1, part2, out);
}

// Round 16
// 126.544 us; speedup vs baseline: 1.2903x; 1.2903x over previous
//
#include <hip/hip_runtime.h>
#include <hip/hip_bf16.h>

__device__ __forceinline__ float sigm(float x) { return 1.f / (1.f + expf(-x)); }
__device__ __forceinline__ float lrelu(float x) { return x > 0.f ? x : 0.2f * x; }
__device__ __forceinline__ float eluf(float x) { return x > 0.f ? x : expf(x) - 1.f; }

#define NEGF (-9e15f)
#define MAXD 40   // deg ~ Binom(4096,1/512): mean 8, sigma 2.8 -> P(deg>40) ~ 1e-28

__device__ __forceinline__ float wave_sum(float v) {
    #pragma unroll
    for (int off = 32; off >= 1; off >>= 1) v += __shfl_xor(v, off);
    return v;
}
__device__ __forceinline__ float wave_max(float v) {
    #pragma unroll
    for (int off = 32; off >= 1; off >>= 1) v = fmaxf(v, __shfl_xor(v, off));
    return v;
}
__device__ __forceinline__ float half_sum(float v) {
    #pragma unroll
    for (int off = 16; off >= 1; off >>= 1) v += __shfl_xor(v, off);
    return v;
}
__device__ __forceinline__ float half_max(float v) {
    #pragma unroll
    for (int off = 16; off >= 1; off >>= 1) v = fmaxf(v, __shfl_xor(v, off));
    return v;
}

// ---------------- K_setup ----------------
// grid 176, block 256
__global__ void k_setup(const float* __restrict__ Wg, const float* __restrict__ Weg,
                        const float* __restrict__ asrc, const float* __restrict__ adst,
                        const float* __restrict__ aedge, const float* __restrict__ Weo,
                        const float* __restrict__ aoe,
                        const float* __restrict__ feat, const float* __restrict__ Wsn,
                        const float* __restrict__ asn, const float* __restrict__ g1W,
                        const float* __restrict__ g1b,
                        float* __restrict__ vs1, float* __restrict__ vd1, float* __restrict__ ve1,
                        float* __restrict__ ve2, int* __restrict__ winner,
                        float* __restrict__ h, float* __restrict__ gate1) {
    int b = blockIdx.x, t = threadIdx.x, w = t >> 6, l = t & 63;
    __shared__ float fr[4][64];
    if (b < 16) {
        int hd = b;
        float s0 = asrc[hd * 128 + l],  s1 = asrc[hd * 128 + 64 + l];
        float d0 = adst[hd * 128 + l],  d1 = adst[hd * 128 + 64 + l];
        float e0 = aedge[hd * 128 + l], e1 = aedge[hd * 128 + 64 + l];
        for (int i = w; i < 64; i += 4) {
            const float* Wr = Wg  + ((size_t)hd * 64 + i) * 128;
            const float* Er = Weg + ((size_t)hd * 64 + i) * 128;
            float w1 = Wr[l], w2 = Wr[64 + l];
            float q1 = Er[l], q2 = Er[64 + l];
            float pS = wave_sum(w1 * s0 + w2 * s1);
            float pD = wave_sum(w1 * d0 + w2 * d1);
            float pE = wave_sum(q1 * e0 + q2 * e1);
            if (l == 0) { vs1[hd * 64 + i] = pS; vd1[hd * 64 + i] = pD; ve1[hd * 64 + i] = pE; }
        }
    } else if (b < 32) {
        int base = (b - 16) * 128;
        float a0 = aoe[l], a1 = aoe[64 + l];
        for (int k = 0; k < 32; k++) {
            int c = base + w * 32 + k;
            const float* Wr = Weo + (size_t)c * 128;
            float p = wave_sum(Wr[l] * a0 + Wr[64 + l] * a1);
            if (l == 0) ve2[c] = p;
        }
    } else if (b < 48) {
        int base = (b - 32) * 4096;
        #pragma unroll
        for (int k = 0; k < 16; k++) winner[base + k * 256 + t] = -1;
    } else {
        int n = (b - 48) * 4 + w;
        fr[w][l] = feat[n * 64 + l];
        __syncthreads();
        float acc = 0.f;
        #pragma unroll 8
        for (int i = 0; i < 64; i++) acc += fr[w][i] * Wsn[i * 64 + l];
        float p = wave_sum(acc * asn[l]);
        float coef = sigm(lrelu(p));
        float hv = eluf(coef * acc);
        h[n * 64 + l] = hv;
        float g = wave_sum(hv * g1W[l]);
        if (l == 0) gate1[n] = sigm(g + g1b[0]);
    }
}

// ---------------- K_mid: wsum1p (b 0..7) | es1/ed1 (b 8..23) | scatter (b 24..31) ----------------
// grid 32, block 512
__global__ void k_mid(const float* __restrict__ h, const float* __restrict__ gate,
                      const float* __restrict__ vs1, const float* __restrict__ vd1,
                      const int* __restrict__ ei,
                      float* __restrict__ part1, float* __restrict__ es1, float* __restrict__ ed1,
                      int* __restrict__ winner) {
    int b = blockIdx.x, t = threadIdx.x;
    if (b < 8) {
        int nb = b, w = t >> 6, l = t & 63;
        __shared__ float mx[8], sm[8], al[512], pt[8][64];
        float g = gate[t];
        float m = wave_max(g);
        if (l == 0) mx[w] = m;
        __syncthreads();
        m = mx[0];
        #pragma unroll
        for (int i = 1; i < 8; i++) m = fmaxf(m, mx[i]);
        float p = expf(g - m);
        float Z = wave_sum(p);
        if (l == 0) sm[w] = Z;
        __syncthreads();
        Z = 0.f;
        #pragma unroll
        for (int i = 0; i < 8; i++) Z += sm[i];
        al[t] = p / Z;
        __syncthreads();
        int r0 = nb * 64 + w * 8;
        float acc = 0.f;
        #pragma unroll
        for (int r = 0; r < 8; r++) acc += al[r0 + r] * h[(r0 + r) * 64 + l];
        pt[w][l] = acc;
        __syncthreads();
        if (t < 64) {
            float o = 0.f;
            #pragma unroll
            for (int q = 0; q < 8; q++) o += pt[q][t];
            part1[nb * 64 + t] = o;
        }
    } else if (b < 24) {
        __shared__ float vsT[64][17], vdT[64][17];
        for (int idx = t; idx < 1024; idx += 512) {
            int i = idx & 63, hd = idx >> 6;
            vsT[i][hd] = vs1[hd * 64 + i];
            vdT[i][hd] = vd1[hd * 64 + i];
        }
        __syncthreads();
        int idx = (b - 8) * 512 + t;
        int n = idx >> 4, hd = idx & 15;
        const float* hr = h + n * 64;
        float aS = 0.f, aD = 0.f;
        #pragma unroll 8
        for (int i = 0; i < 64; i++) {
            float hv = hr[i];
            aS += hv * vsT[i][hd];
            aD += hv * vdT[i][hd];
        }
        es1[hd * 512 + n] = aS;
        ed1[hd * 512 + n] = aD;
    } else {
        int e = (b - 24) * 512 + t;
        int s = ei[e] >> 1, d = ei[4096 + e] >> 1;
        atomicMax(&winner[s * 256 + d], e);
    }
}

// ---------------- K_attn_ze: attn_z (b 0..511) | edot (b 512..1023) [R14-proven] ----------------
// grid 1024, block 512
__global__ void k_attn_ze(const float* __restrict__ adj, const float* __restrict__ n2n,
                          const float* __restrict__ h, const float* __restrict__ ve1,
                          const float* __restrict__ es1, const float* __restrict__ ed1,
                          const float* __restrict__ eattr, const float* __restrict__ Weg,
                          const float* __restrict__ ve2,
                          float* __restrict__ z, float* __restrict__ d2) {
    int b = blockIdx.x, t = threadIdx.x, w = t >> 6, l = t & 63;
    if (b >= 512) {
        // edot: 8 edges/block; thread = (hd = t>>5, q = t&31 -> 4 channels); float4 acc[8] = 32 regs
        int e0 = (b - 512) * 8;
        int hd = t >> 5, q = t & 31;
        __shared__ float ea[8][64];
        __shared__ float sd2[8][8];
        ea[t >> 6][t & 63] = eattr[(size_t)(e0 + (t >> 6)) * 64 + (t & 63)];
        __syncthreads();
        float4 acc[8];
        #pragma unroll
        for (int r = 0; r < 8; r++) acc[r] = make_float4(0.f, 0.f, 0.f, 0.f);
        const float4* W4 = (const float4*)Weg + (size_t)hd * 2048 + q;
        #pragma unroll 4
        for (int i = 0; i < 64; i++) {
            float4 wv = W4[i * 32];
            #pragma unroll
            for (int r = 0; r < 8; r++) {
                float a = ea[r][i];
                acc[r].x += a * wv.x; acc[r].y += a * wv.y;
                acc[r].z += a * wv.z; acc[r].w += a * wv.w;
            }
        }
        float4 v2 = ((const float4*)ve2)[hd * 32 + q];
        #pragma unroll
        for (int r = 0; r < 8; r++) {
            float p = eluf(acc[r].x) * v2.x + eluf(acc[r].y) * v2.y
                    + eluf(acc[r].z) * v2.z + eluf(acc[r].w) * v2.w;
            p = wave_sum(p);
            if (l == 0) sd2[r][w] = p;
        }
        __syncthreads();
        if (t < 8) {
            float s8 = 0.f;
            #pragma unroll
            for (int k = 0; k < 8; k++) s8 += sd2[t][k];
            d2[e0 + t] = s8;
        }
        return;
    }
    int s = b;
    __shared__ float vlT[64][17];
    __shared__ float hrow[MAXD][65], nrow[MAXD][65];
    __shared__ float eh[16][48], ah[16][48];
    __shared__ float esr[16];
    __shared__ int dlist[MAXD];
    __shared__ int wbase[8];
    __shared__ int nnz_s;
    __shared__ float part[8][64];

    for (int idx = t; idx < 1024; idx += 512) vlT[idx & 63][idx >> 6] = ve1[(idx >> 6) * 64 + (idx & 63)];
    if (t < 16) esr[t] = es1[t * 512 + s];
    float a = adj[s * 512 + t];
    unsigned long long mask = __ballot(a > 0.f);
    if (l == 0) wbase[w] = __popcll(mask);
    __syncthreads();
    if (t == 0) {
        int run = 0;
        #pragma unroll
        for (int i = 0; i < 8; i++) { int c = wbase[i]; wbase[i] = run; run += c; }
        nnz_s = run;
    }
    __syncthreads();
    if (a > 0.f) {
        int slot = wbase[w] + __popcll(mask & ((1ULL << l) - 1ULL));
        if (slot < MAXD) dlist[slot] = t;
    }
    __syncthreads();
    int nnz = min(nnz_s, MAXD);

    if (nnz == 0) {
        int i = t & 63, q = t >> 6;
        float acc = 0.f;
        for (int d = q * 64; d < q * 64 + 64; d++) acc += h[d * 64 + i];
        part[q][i] = acc;
        __syncthreads();
        if (t < 64) {
            float sum = 0.f;
            #pragma unroll
            for (int q2 = 0; q2 < 8; q2++) sum += part[q2][t];
            float v = sum * (1.f / 512.f);
            for (int hd = 0; hd < 16; hd++) z[(size_t)s * 1024 + hd * 64 + t] = v;
        }
        return;
    }

    for (int base = 0; base < nnz; base += 8) {
        int j = base + (t >> 6);
        if (j < nnz) {
            int d = dlist[j];
            hrow[j][l] = h[d * 64 + l];
            nrow[j][l] = n2n[((size_t)s * 512 + d) * 64 + l];
        }
    }
    __syncthreads();
    for (int jb = 0; jb < nnz; jb += 32) {
        int j = jb + (t >> 4), hd = t & 15;
        if (j < nnz) {
            float ee = 0.f;
            #pragma unroll 8
            for (int i = 0; i < 64; i++) ee += nrow[j][i] * vlT[i][hd];
            eh[hd][j] = lrelu(esr[hd] + ed1[hd * 512 + dlist[j]] + ee);
        }
    }
    __syncthreads();
    {
        int hd = t >> 5, lane32 = t & 31;
        float v0 = (lane32 < nnz) ? eh[hd][lane32] : -1e30f;
        float v1 = (lane32 + 32 < nnz) ? eh[hd][lane32 + 32] : -1e30f;
        float m = half_max(fmaxf(v0, v1));
        float p0 = (lane32 < nnz) ? expf(v0 - m) : 0.f;
        float p1 = (lane32 + 32 < nnz) ? expf(v1 - m) : 0.f;
        float Z = half_sum(p0 + p1);
        float inv = 1.f / Z;
        if (lane32 < nnz) ah[hd][lane32] = p0 * inv;
        if (lane32 + 32 < nnz) ah[hd][lane32 + 32] = p1 * inv;
    }
    __syncthreads();
    int hd = t >> 5, i0 = t & 31;
    float a0 = 0.f, a1 = 0.f;
    for (int j = 0; j < nnz; j++) {
        float aj = ah[hd][j];
        a0 += aj * hrow[j][i0];
        a1 += aj * hrow[j][i0 + 32];
    }
    z[(size_t)s * 1024 + hd * 64 + i0]      = a0;
    z[(size_t)s * 1024 + hd * 64 + i0 + 32] = a1;
}

// ---------------- K_houtg: hout[s][hd*128+c] = elu( z[s][hd]·Wg[hd][:,c] ) [R14] ----------------
// grid (64, 16), block 128
__global__ void k_houtg(const float* __restrict__ z, const float* __restrict__ Wg,
                        float* __restrict__ hout) {
    int sb = blockIdx.x, hd = blockIdx.y, c = threadIdx.x;
    __shared__ float zt[8][64];
    int s0 = sb * 8;
    for (int idx = c; idx < 512; idx += 128) {
        int r = idx >> 6, i = idx & 63;
        zt[r][i] = z[(size_t)(s0 + r) * 1024 + hd * 64 + i];
    }
    __syncthreads();
    float acc[8] = {0, 0, 0, 0, 0, 0, 0, 0};
    const float* W = Wg + (size_t)hd * 8192 + c;
    #pragma unroll 8
    for (int i = 0; i < 64; i++) {
        float wv = W[(size_t)i * 128];
        #pragma unroll
        for (int r = 0; r < 8; r++) acc[r] += zt[r][i] * wv;
    }
    #pragma unroll
    for (int r = 0; r < 8; r++)
        hout[(size_t)(s0 + r) * 2048 + hd * 128 + c] = eluf(acc[r]);
}

// ---------------- K_big2p: pool1 + gate2 + wh2 fused (2 x1p rows / block) [R15-proven] ----------------
// grid 128, block 1024
__global__ void k_big2p(const float* __restrict__ hout1, const float* __restrict__ Wp1,
                        const float* __restrict__ bp1, const float* __restrict__ g2W,
                        const float* __restrict__ g2b, const float* __restrict__ Wo,
                        const float* __restrict__ aos, const float* __restrict__ aod,
                        float* __restrict__ x1p, float* __restrict__ gate2,
                        float* __restrict__ Wh2, float* __restrict__ es2, float* __restrict__ ed2) {
    int b = blockIdx.x, t = threadIdx.x;
    __shared__ float hs[4][2048];
    __shared__ float xr[2][2048];
    __shared__ float part[8][2][128];
    __shared__ float red[16], rs[4], rd[4];
    int n0 = 2 * b;
    for (int idx = t; idx < 8192; idx += 1024)
        hs[idx >> 11][idx & 2047] = hout1[(size_t)(4 * b) * 2048 + idx];
    __syncthreads();
    int g = t >> 9, tt = t & 511;
    float p = 0.f;
    for (int f = tt; f < 2048; f += 512)
        p += hs[2 * g][f] * Wp1[f] + hs[2 * g + 1][f] * Wp1[2048 + f];
    p = wave_sum(p);
    if ((t & 63) == 0) red[t >> 6] = p;
    __syncthreads();
    float s8 = 0.f;
    #pragma unroll
    for (int k2 = 0; k2 < 8; k2++) s8 += red[g * 8 + k2];
    float sc = sigm(s8 + bp1[0]);
    __syncthreads();
    float pg = 0.f;
    for (int f = tt; f < 2048; f += 512) {
        float v = (hs[2 * g][f] + hs[2 * g + 1][f]) * sc;
        xr[g][f] = v;
        x1p[(size_t)(n0 + g) * 2048 + f] = v;
        pg += v * g2W[f];
    }
    pg = wave_sum(pg);
    if ((t & 63) == 0) red[t >> 6] = pg;
    __syncthreads();
    if (t == 0 || t == 512) {
        float sg8 = 0.f;
        #pragma unroll
        for (int k2 = 0; k2 < 8; k2++) sg8 += red[g * 8 + k2];
        gate2[n0 + g] = sigm(sg8 + g2b[0]);
    }
    int ks = t >> 7, c = t & 127;
    float a0 = 0.f, a1 = 0.f;
    const float* W  = Wo + (size_t)(ks * 256) * 128 + c;
    const float* x0 = xr[0] + ks * 256;
    const float* x1 = xr[1] + ks * 256;
    #pragma unroll 8
    for (int i = 0; i < 256; i++) { float w = W[(size_t)i * 128]; a0 += x0[i] * w; a1 += x1[i] * w; }
    part[ks][0][c] = a0;
    part[ks][1][c] = a1;
    __syncthreads();
    if (t < 256) {
        int r = t >> 7, cc = t & 127;
        float a = 0.f;
        #pragma unroll
        for (int k2 = 0; k2 < 8; k2++) a += part[k2][r][cc];
        Wh2[(n0 + r) * 128 + cc] = a;
        float ps = wave_sum(a * aos[cc]);
        float pd = wave_sum(a * aod[cc]);
        if ((t & 63) == 0) { rs[t >> 6] = ps; rd[t >> 6] = pd; }
    }
    __syncthreads();
    if (t == 0) { es2[n0] = rs[0] + rs[1]; ed2[n0] = rd[0] + rd[1]; }
    if (t == 1) { es2[n0 + 1] = rs[2] + rs[3]; ed2[n0 + 1] = rd[2] + rd[3]; }
}

// ---------------- K_fin: attn2 (b 0..255) | wsum2p (b 256..319) [R15-proven] ----------------
// grid 320, block 256
__global__ void k_fin(const int* __restrict__ winner, const float* __restrict__ d2,
                      const float* __restrict__ es2, const float* __restrict__ ed2,
                      const float* __restrict__ Wh2, const float* __restrict__ gate2,
                      const float* __restrict__ x1p,
                      float* __restrict__ part2, float* __restrict__ hout2) {
    int b = blockIdx.x, t = threadIdx.x;
    if (b < 256) {
        int s = b, w = t >> 6, l = t & 63;
        __shared__ float mx[4], sm[4], at[256], part[2][128];
        int win = winner[s * 256 + t];
        float e;
        if (win >= 0) e = lrelu(es2[s] + ed2[t] + d2[win]);
        else e = NEGF;
        float m = wave_max(e);
        if (l == 0) mx[w] = m;
        __syncthreads();
        m = fmaxf(fmaxf(mx[0], mx[1]), fmaxf(mx[2], mx[3]));
        float p = expf(e - m);
        float Z = wave_sum(p);
        if (l == 0) sm[w] = Z;
        __syncthreads();
        Z = sm[0] + sm[1] + sm[2] + sm[3];
        at[t] = p / Z;
        __syncthreads();
        int c = t & 127, hf = t >> 7;
        float acc = 0.f;
        for (int d = hf * 128; d < hf * 128 + 128; d++)
            acc += at[d] * Wh2[d * 128 + c];
        part[hf][c] = acc;
        __syncthreads();
        if (t < 128) hout2[s * 128 + t] = part[0][t] + part[1][t];   // concat=False: no elu
    } else {
        int tile = b - 256;
        int cb = tile >> 3, nb = tile & 7;
        __shared__ float mx2[4], sm2[4], al[256];
        int w = t >> 6, l = t & 63;
        float g = gate2[t];
        float m = wave_max(g);
        if (l == 0) mx2[w] = m;
        __syncthreads();
        m = fmaxf(fmaxf(mx2[0], mx2[1]), fmaxf(mx2[2], mx2[3]));
        float p = expf(g - m);
        float Z = wave_sum(p);
        if (l == 0) sm2[w] = Z;
        __syncthreads();
        Z = sm2[0] + sm2[1] + sm2[2] + sm2[3];
        al[t] = p / Z;
        __syncthreads();
        int c = cb * 256 + t;
        int n0 = nb * 32;
        float acc = 0.f;
        #pragma unroll 8
        for (int n = n0; n < n0 + 32; n++) acc += al[n] * x1p[(size_t)n * 2048 + c];
        part2[nb * 2048 + c] = acc;
    }
}

// ---------------- K_tail: pool2+gate3+gattn3 (b 0) | wsumr (b 1..9) [R15-proven] ----------------
// grid 10, block 512
__global__ void k_tail(const float* __restrict__ hout2, const float* __restrict__ Wp,
                       const float* __restrict__ bp, const float* __restrict__ g3W,
                       const float* __restrict__ g3b, const float* __restrict__ part1,
                       const float* __restrict__ part2, float* __restrict__ out) {
    int t = threadIdx.x, w = t >> 6, l = t & 63;
    if (blockIdx.x > 0) {
        int rb = blockIdx.x - 1;
        if (rb == 0) {
            if (t < 64) {
                float o = 0.f;
                #pragma unroll
                for (int nb = 0; nb < 8; nb++) o += part1[nb * 64 + t];
                out[t] = o;
            }
        } else if (t < 256) {
            int c = (rb - 1) * 256 + t;
            float o = 0.f;
            #pragma unroll
            for (int nb = 0; nb < 8; nb++) o += part2[nb * 2048 + c];
            out[64 + c] = o;
        }
        return;
    }
    __shared__ float x2s[128][129];
    __shared__ float gt[128];
    __shared__ float mx[2], sm[2], al[128], part[4][128];
    float bpv = bp[0], g3bv = g3b[0];
    for (int rr = 0; rr < 16; rr++) {
        int k = w * 16 + rr;
        float a0  = hout2[(size_t)(2 * k) * 128 + l];
        float a0b = hout2[(size_t)(2 * k) * 128 + 64 + l];
        float a1  = hout2[(size_t)(2 * k + 1) * 128 + l];
        float a1b = hout2[(size_t)(2 * k + 1) * 128 + 64 + l];
        float p = a0 * Wp[l] + a0b * Wp[64 + l] + a1 * Wp[128 + l] + a1b * Wp[192 + l];
        p = wave_sum(p);
        float sc = sigm(p + bpv);
        float v  = (a0 + a1) * sc;
        float vb = (a0b + a1b) * sc;
        x2s[k][l] = v;
        x2s[k][64 + l] = vb;
        float g = wave_sum(v * g3W[l] + vb * g3W[64 + l]);
        if (l == 0) gt[k] = sigm(g + g3bv);
    }
    __syncthreads();
    if (t < 128) {
        float g = gt[t];
        float m = wave_max(g);
        if (l == 0) mx[w] = m;
    }
    __syncthreads();
    if (t < 128) {
        float g = gt[t];
        float m = fmaxf(mx[0], mx[1]);
        float p = expf(g - m);
        float Z = wave_sum(p);
        if (l == 0) sm[w] = Z;
        al[t] = p;
    }
    __syncthreads();
    float invZ = 1.f / (sm[0] + sm[1]);
    int q = t >> 7, c = t & 127;
    float acc = 0.f;
    for (int n = q * 32; n < q * 32 + 32; n++) acc += al[n] * x2s[n][c];
    part[q][c] = acc * invZ;
    __syncthreads();
    if (t < 128) out[2112 + t] = part[0][t] + part[1][t] + part[2][t] + part[3][t];
}

extern "C" void kernel_launch(void* const* d_in, const int* in_sizes, int n_in,
                              void* d_out, int out_size, void* d_ws, size_t ws_size,
                              hipStream_t stream) {
    const float* feat  = (const float*)d_in[0];
    const int*   eidx  = (const int*)d_in[1];
    const float* eattr = (const float*)d_in[2];
    const float* adj   = (const float*)d_in[3];
    const float* n2n   = (const float*)d_in[4];
    const float* Wsn   = (const float*)d_in[5];
    const float* asn   = (const float*)d_in[6];
    const float* Wg    = (const float*)d_in[7];
    const float* Weg   = (const float*)d_in[8];
    const float* asrc  = (const float*)d_in[9];
    const float* adst  = (const float*)d_in[10];
    const float* aedge = (const float*)d_in[11];
    const float* Wp1   = (const float*)d_in[12];
    const float* bp1   = (const float*)d_in[13];
    const float* Wo    = (const float*)d_in[14];
    const float* Weo   = (const float*)d_in[15];
    const float* aos   = (const float*)d_in[16];
    const float* aod   = (const float*)d_in[17];
    const float* aoe   = (const float*)d_in[18];
    const float* Wp2   = (const float*)d_in[19];
    const float* bp2   = (const float*)d_in[20];
    const float* g1W   = (const float*)d_in[21];
    const float* g1b   = (const float*)d_in[22];
    const float* g2W   = (const float*)d_in[23];
    const float* g2b   = (const float*)d_in[24];
    const float* g3W   = (const float*)d_in[25];
    const float* g3b   = (const float*)d_in[26];
    float* out = (float*)d_out;

    char* ws = (char*)d_ws;
    float* h      = (float*)(ws + 0x0000000);   // 128KB
    float* z      = (float*)(ws + 0x0020000);   // 2MB
    float* ve1    = (float*)(ws + 0x0430000);   // 4KB
    float* ve2    = (float*)(ws + 0x0431000);   // 8KB
    float* gate1  = (float*)(ws + 0x0433000);   // 2KB
    float* gate2  = (float*)(ws + 0x0434000);   // 1KB
    float* vs1    = (float*)(ws + 0x0436000);   // 4KB
    float* vd1    = (float*)(ws + 0x0438000);   // 4KB
    float* es1    = (float*)(ws + 0x0440000);   // 32KB
    float* ed1    = (float*)(ws + 0x0448000);   // 32KB
    float* hout1  = (float*)(ws + 0x1440000);   // 4MB
    float* d2     = (float*)(ws + 0x1840000);   // 16KB
    float* x1p    = (float*)(ws + 0x1850000);   // 2MB
    int*   winner = (int*)  (ws + 0x1A50000);   // 256KB
    float* Wh2    = (float*)(ws + 0x1A90000);   // 128KB
    float* es2    = (float*)(ws + 0x1AB0000);   // 1KB
    float* ed2    = (float*)(ws + 0x1AB1000);   // 1KB
    float* hout2  = (float*)(ws + 0x1AB2000);   // 128KB
    float* part2  = (float*)(ws + 0x1AE2000);   // 64KB
    float* part1  = (float*)(ws + 0x1AF2000);   // 2KB

    k_setup  <<<176, 256, 0, stream>>>(Wg, Weg, asrc, adst, aedge, Weo, aoe,
                                       feat, Wsn, asn, g1W, g1b,
                                       vs1, vd1, ve1, ve2, winner, h, gate1);
    k_mid    <<<32, 512, 0, stream>>>(h, gate1, vs1, vd1, eidx, part1, es1, ed1, winner);
    k_attn_ze<<<1024, 512, 0, stream>>>(adj, n2n, h, ve1, es1, ed1, eattr, Weg, ve2, z, d2);
    k_houtg  <<<dim3(64, 16), 128, 0, stream>>>(z, Wg, hout1);
    k_big2p  <<<128, 1024, 0, stream>>>(hout1, Wp1, bp1, g2W, g2b, Wo, aos, aod,
                                        x1p, gate2, Wh2, es2, ed2);
    k_fin    <<<320, 256, 0, stream>>>(winner, d2, es2, ed2, Wh2, gate2, x1p, part2, hout2);
    k_tail   <<<10, 512, 0, stream>>>(hout2, Wp2, bp2, g3W, g3b, part1, part2, out);
}

// Round 17
// 121.429 us; speedup vs baseline: 1.3447x; 1.0421x over previous
//
#include <hip/hip_runtime.h>
#include <hip/hip_bf16.h>

__device__ __forceinline__ float sigm(float x) { return 1.f / (1.f + expf(-x)); }
__device__ __forceinline__ float lrelu(float x) { return x > 0.f ? x : 0.2f * x; }
__device__ __forceinline__ float eluf(float x) { return x > 0.f ? x : expf(x) - 1.f; }

#define NEGF (-9e15f)
#define MAXD 40   // deg ~ Binom(4096,1/512): mean 8, sigma 2.8 -> P(deg>40) ~ 1e-28

__device__ __forceinline__ float wave_sum(float v) {
    #pragma unroll
    for (int off = 32; off >= 1; off >>= 1) v += __shfl_xor(v, off);
    return v;
}
__device__ __forceinline__ float wave_max(float v) {
    #pragma unroll
    for (int off = 32; off >= 1; off >>= 1) v = fmaxf(v, __shfl_xor(v, off));
    return v;
}
__device__ __forceinline__ float half_sum(float v) {
    #pragma unroll
    for (int off = 16; off >= 1; off >>= 1) v += __shfl_xor(v, off);
    return v;
}
__device__ __forceinline__ float half_max(float v) {
    #pragma unroll
    for (int off = 16; off >= 1; off >>= 1) v = fmaxf(v, __shfl_xor(v, off));
    return v;
}

// ---------------- K_setup ----------------
// grid 176, block 256
__global__ void k_setup(const float* __restrict__ Wg, const float* __restrict__ Weg,
                        const float* __restrict__ asrc, const float* __restrict__ adst,
                        const float* __restrict__ aedge, const float* __restrict__ Weo,
                        const float* __restrict__ aoe,
                        const float* __restrict__ feat, const float* __restrict__ Wsn,
                        const float* __restrict__ asn, const float* __restrict__ g1W,
                        const float* __restrict__ g1b,
                        float* __restrict__ vs1, float* __restrict__ vd1, float* __restrict__ ve1,
                        float* __restrict__ ve2, int* __restrict__ winner,
                        float* __restrict__ h, float* __restrict__ gate1) {
    int b = blockIdx.x, t = threadIdx.x, w = t >> 6, l = t & 63;
    __shared__ float fr[4][64];
    if (b < 16) {
        int hd = b;
        float s0 = asrc[hd * 128 + l],  s1 = asrc[hd * 128 + 64 + l];
        float d0 = adst[hd * 128 + l],  d1 = adst[hd * 128 + 64 + l];
        float e0 = aedge[hd * 128 + l], e1 = aedge[hd * 128 + 64 + l];
        for (int i = w; i < 64; i += 4) {
            const float* Wr = Wg  + ((size_t)hd * 64 + i) * 128;
            const float* Er = Weg + ((size_t)hd * 64 + i) * 128;
            float w1 = Wr[l], w2 = Wr[64 + l];
            float q1 = Er[l], q2 = Er[64 + l];
            float pS = wave_sum(w1 * s0 + w2 * s1);
            float pD = wave_sum(w1 * d0 + w2 * d1);
            float pE = wave_sum(q1 * e0 + q2 * e1);
            if (l == 0) { vs1[hd * 64 + i] = pS; vd1[hd * 64 + i] = pD; ve1[hd * 64 + i] = pE; }
        }
    } else if (b < 32) {
        int base = (b - 16) * 128;
        float a0 = aoe[l], a1 = aoe[64 + l];
        for (int k = 0; k < 32; k++) {
            int c = base + w * 32 + k;
            const float* Wr = Weo + (size_t)c * 128;
            float p = wave_sum(Wr[l] * a0 + Wr[64 + l] * a1);
            if (l == 0) ve2[c] = p;
        }
    } else if (b < 48) {
        int base = (b - 32) * 4096;
        #pragma unroll
        for (int k = 0; k < 16; k++) winner[base + k * 256 + t] = -1;
    } else {
        int n = (b - 48) * 4 + w;
        fr[w][l] = feat[n * 64 + l];
        __syncthreads();
        float acc = 0.f;
        #pragma unroll 8
        for (int i = 0; i < 64; i++) acc += fr[w][i] * Wsn[i * 64 + l];
        float p = wave_sum(acc * asn[l]);
        float coef = sigm(lrelu(p));
        float hv = eluf(coef * acc);
        h[n * 64 + l] = hv;
        float g = wave_sum(hv * g1W[l]);
        if (l == 0) gate1[n] = sigm(g + g1b[0]);
    }
}

// ---------------- K_mid: wsum1p (b 0..7) | es1/ed1 (b 8..23) | scatter (b 24..31) ----------------
// grid 32, block 512
__global__ void k_mid(const float* __restrict__ h, const float* __restrict__ gate,
                      const float* __restrict__ vs1, const float* __restrict__ vd1,
                      const int* __restrict__ ei,
                      float* __restrict__ part1, float* __restrict__ es1, float* __restrict__ ed1,
                      int* __restrict__ winner) {
    int b = blockIdx.x, t = threadIdx.x;
    if (b < 8) {
        int nb = b, w = t >> 6, l = t & 63;
        __shared__ float mx[8], sm[8], al[512], pt[8][64];
        float g = gate[t];
        float m = wave_max(g);
        if (l == 0) mx[w] = m;
        __syncthreads();
        m = mx[0];
        #pragma unroll
        for (int i = 1; i < 8; i++) m = fmaxf(m, mx[i]);
        float p = expf(g - m);
        float Z = wave_sum(p);
        if (l == 0) sm[w] = Z;
        __syncthreads();
        Z = 0.f;
        #pragma unroll
        for (int i = 0; i < 8; i++) Z += sm[i];
        al[t] = p / Z;
        __syncthreads();
        int r0 = nb * 64 + w * 8;
        float acc = 0.f;
        #pragma unroll
        for (int r = 0; r < 8; r++) acc += al[r0 + r] * h[(r0 + r) * 64 + l];
        pt[w][l] = acc;
        __syncthreads();
        if (t < 64) {
            float o = 0.f;
            #pragma unroll
            for (int q = 0; q < 8; q++) o += pt[q][t];
            part1[nb * 64 + t] = o;
        }
    } else if (b < 24) {
        __shared__ float vsT[64][17], vdT[64][17];
        for (int idx = t; idx < 1024; idx += 512) {
            int i = idx & 63, hd = idx >> 6;
            vsT[i][hd] = vs1[hd * 64 + i];
            vdT[i][hd] = vd1[hd * 64 + i];
        }
        __syncthreads();
        int idx = (b - 8) * 512 + t;
        int n = idx >> 4, hd = idx & 15;
        const float* hr = h + n * 64;
        float aS = 0.f, aD = 0.f;
        #pragma unroll 8
        for (int i = 0; i < 64; i++) {
            float hv = hr[i];
            aS += hv * vsT[i][hd];
            aD += hv * vdT[i][hd];
        }
        es1[hd * 512 + n] = aS;
        ed1[hd * 512 + n] = aD;
    } else {
        int e = (b - 24) * 512 + t;
        int s = ei[e] >> 1, d = ei[4096 + e] >> 1;
        atomicMax(&winner[s * 256 + d], e);
    }
}

// ---------------- K_attn_ze: attn_z (b 0..511) | edot (b 512..1023) [R14-proven] ----------------
// grid 1024, block 512
__global__ void k_attn_ze(const float* __restrict__ adj, const float* __restrict__ n2n,
                          const float* __restrict__ h, const float* __restrict__ ve1,
                          const float* __restrict__ es1, const float* __restrict__ ed1,
                          const float* __restrict__ eattr, const float* __restrict__ Weg,
                          const float* __restrict__ ve2,
                          float* __restrict__ z, float* __restrict__ d2) {
    int b = blockIdx.x, t = threadIdx.x, w = t >> 6, l = t & 63;
    if (b >= 512) {
        int e0 = (b - 512) * 8;
        int hd = t >> 5, q = t & 31;
        __shared__ float ea[8][64];
        __shared__ float sd2[8][8];
        ea[t >> 6][t & 63] = eattr[(size_t)(e0 + (t >> 6)) * 64 + (t & 63)];
        __syncthreads();
        float4 acc[8];
        #pragma unroll
        for (int r = 0; r < 8; r++) acc[r] = make_float4(0.f, 0.f, 0.f, 0.f);
        const float4* W4 = (const float4*)Weg + (size_t)hd * 2048 + q;
        #pragma unroll 4
        for (int i = 0; i < 64; i++) {
            float4 wv = W4[i * 32];
            #pragma unroll
            for (int r = 0; r < 8; r++) {
                float a = ea[r][i];
                acc[r].x += a * wv.x; acc[r].y += a * wv.y;
                acc[r].z += a * wv.z; acc[r].w += a * wv.w;
            }
        }
        float4 v2 = ((const float4*)ve2)[hd * 32 + q];
        #pragma unroll
        for (int r = 0; r < 8; r++) {
            float p = eluf(acc[r].x) * v2.x + eluf(acc[r].y) * v2.y
                    + eluf(acc[r].z) * v2.z + eluf(acc[r].w) * v2.w;
            p = wave_sum(p);
            if (l == 0) sd2[r][w] = p;
        }
        __syncthreads();
        if (t < 8) {
            float s8 = 0.f;
            #pragma unroll
            for (int k = 0; k < 8; k++) s8 += sd2[t][k];
            d2[e0 + t] = s8;
        }
        return;
    }
    int s = b;
    __shared__ float vlT[64][17];
    __shared__ float hrow[MAXD][65], nrow[MAXD][65];
    __shared__ float eh[16][48], ah[16][48];
    __shared__ float esr[16];
    __shared__ int dlist[MAXD];
    __shared__ int wbase[8];
    __shared__ int nnz_s;
    __shared__ float part[8][64];

    for (int idx = t; idx < 1024; idx += 512) vlT[idx & 63][idx >> 6] = ve1[(idx >> 6) * 64 + (idx & 63)];
    if (t < 16) esr[t] = es1[t * 512 + s];
    float a = adj[s * 512 + t];
    unsigned long long mask = __ballot(a > 0.f);
    if (l == 0) wbase[w] = __popcll(mask);
    __syncthreads();
    if (t == 0) {
        int run = 0;
        #pragma unroll
        for (int i = 0; i < 8; i++) { int c = wbase[i]; wbase[i] = run; run += c; }
        nnz_s = run;
    }
    __syncthreads();
    if (a > 0.f) {
        int slot = wbase[w] + __popcll(mask & ((1ULL << l) - 1ULL));
        if (slot < MAXD) dlist[slot] = t;
    }
    __syncthreads();
    int nnz = min(nnz_s, MAXD);

    if (nnz == 0) {
        int i = t & 63, q = t >> 6;
        float acc = 0.f;
        for (int d = q * 64; d < q * 64 + 64; d++) acc += h[d * 64 + i];
        part[q][i] = acc;
        __syncthreads();
        if (t < 64) {
            float sum = 0.f;
            #pragma unroll
            for (int q2 = 0; q2 < 8; q2++) sum += part[q2][t];
            float v = sum * (1.f / 512.f);
            for (int hd = 0; hd < 16; hd++) z[(size_t)s * 1024 + hd * 64 + t] = v;
        }
        return;
    }

    for (int base = 0; base < nnz; base += 8) {
        int j = base + (t >> 6);
        if (j < nnz) {
            int d = dlist[j];
            hrow[j][l] = h[d * 64 + l];
            nrow[j][l] = n2n[((size_t)s * 512 + d) * 64 + l];
        }
    }
    __syncthreads();
    for (int jb = 0; jb < nnz; jb += 32) {
        int j = jb + (t >> 4), hd = t & 15;
        if (j < nnz) {
            float ee = 0.f;
            #pragma unroll 8
            for (int i = 0; i < 64; i++) ee += nrow[j][i] * vlT[i][hd];
            eh[hd][j] = lrelu(esr[hd] + ed1[hd * 512 + dlist[j]] + ee);
        }
    }
    __syncthreads();
    {
        int hd = t >> 5, lane32 = t & 31;
        float v0 = (lane32 < nnz) ? eh[hd][lane32] : -1e30f;
        float v1 = (lane32 + 32 < nnz) ? eh[hd][lane32 + 32] : -1e30f;
        float m = half_max(fmaxf(v0, v1));
        float p0 = (lane32 < nnz) ? expf(v0 - m) : 0.f;
        float p1 = (lane32 + 32 < nnz) ? expf(v1 - m) : 0.f;
        float Z = half_sum(p0 + p1);
        float inv = 1.f / Z;
        if (lane32 < nnz) ah[hd][lane32] = p0 * inv;
        if (lane32 + 32 < nnz) ah[hd][lane32 + 32] = p1 * inv;
    }
    __syncthreads();
    int hd = t >> 5, i0 = t & 31;
    float a0 = 0.f, a1 = 0.f;
    for (int j = 0; j < nnz; j++) {
        float aj = ah[hd][j];
        a0 += aj * hrow[j][i0];
        a1 += aj * hrow[j][i0 + 32];
    }
    z[(size_t)s * 1024 + hd * 64 + i0]      = a0;
    z[(size_t)s * 1024 + hd * 64 + i0 + 32] = a1;
}

// ---------------- K_big2p: hout(z@Wg) + pool1 + gate2 + wh2 fused, hout1 never global ----------------
// grid 128, block 1024. LDS phased union: [zt 16KB | hs 32KB] -> [xr 16KB | hs 32KB | part 8KB]
__global__ void k_big2p(const float* __restrict__ z, const float* __restrict__ Wg,
                        const float* __restrict__ Wp1, const float* __restrict__ bp1,
                        const float* __restrict__ g2W, const float* __restrict__ g2b,
                        const float* __restrict__ Wo,
                        const float* __restrict__ aos, const float* __restrict__ aod,
                        float* __restrict__ x1p, float* __restrict__ gate2,
                        float* __restrict__ Wh2, float* __restrict__ es2, float* __restrict__ ed2) {
    int b = blockIdx.x, t = threadIdx.x;
    __shared__ __align__(16) char smem[57600];
    float (*zt)[1024]    = reinterpret_cast<float(*)[1024]>(smem);          // 16KB (phase A)
    float (*xr)[2048]    = reinterpret_cast<float(*)[2048]>(smem);          // 16KB (phase B, reuses zt)
    float (*hs)[2048]    = reinterpret_cast<float(*)[2048]>(smem + 16384);  // 32KB
    float (*part)[2][128]= reinterpret_cast<float(*)[2][128]>(smem + 49152);// 8KB
    float *red = reinterpret_cast<float*>(smem + 57344);                    // 16 floats
    float *rs  = reinterpret_cast<float*>(smem + 57408);                    // 4
    float *rd  = reinterpret_cast<float*>(smem + 57424);                    // 4
    int n0 = 2 * b;
    // phase A: load z rows 4b..4b+3, compute hs = elu(z @ Wg)
    for (int idx = t; idx < 4096; idx += 1024)
        zt[idx >> 10][idx & 1023] = z[(size_t)(4 * b) * 1024 + idx];
    __syncthreads();
    {
        int c = t & 127, g8 = t >> 7;            // 8 head-groups x 128 cols
        #pragma unroll
        for (int it = 0; it < 2; it++) {
            int hd = g8 + 8 * it;
            const float* W = Wg + (size_t)hd * 8192 + c;
            const float* z0 = &zt[0][hd * 64];
            const float* z1 = &zt[1][hd * 64];
            const float* z2 = &zt[2][hd * 64];
            const float* z3 = &zt[3][hd * 64];
            float a0 = 0.f, a1 = 0.f, a2 = 0.f, a3 = 0.f;
            #pragma unroll 8
            for (int i = 0; i < 64; i++) {
                float wv = W[(size_t)i * 128];
                a0 += z0[i] * wv; a1 += z1[i] * wv;
                a2 += z2[i] * wv; a3 += z3[i] * wv;
            }
            hs[0][hd * 128 + c] = eluf(a0);
            hs[1][hd * 128 + c] = eluf(a1);
            hs[2][hd * 128 + c] = eluf(a2);
            hs[3][hd * 128 + c] = eluf(a3);
        }
    }
    __syncthreads();   // hs complete; zt consumed -> xr region free
    // phase B: pool1 + gate2 + wh2 (R15-proven body, hs in LDS)
    int g = t >> 9, tt = t & 511;
    float p = 0.f;
    for (int f = tt; f < 2048; f += 512)
        p += hs[2 * g][f] * Wp1[f] + hs[2 * g + 1][f] * Wp1[2048 + f];
    p = wave_sum(p);
    if ((t & 63) == 0) red[t >> 6] = p;
    __syncthreads();
    float s8 = 0.f;
    #pragma unroll
    for (int k2 = 0; k2 < 8; k2++) s8 += red[g * 8 + k2];
    float sc = sigm(s8 + bp1[0]);
    __syncthreads();
    float pg = 0.f;
    for (int f = tt; f < 2048; f += 512) {
        float v = (hs[2 * g][f] + hs[2 * g + 1][f]) * sc;
        xr[g][f] = v;
        x1p[(size_t)(n0 + g) * 2048 + f] = v;
        pg += v * g2W[f];
    }
    pg = wave_sum(pg);
    if ((t & 63) == 0) red[t >> 6] = pg;
    __syncthreads();
    if (t == 0 || t == 512) {
        float sg8 = 0.f;
        #pragma unroll
        for (int k2 = 0; k2 < 8; k2++) sg8 += red[g * 8 + k2];
        gate2[n0 + g] = sigm(sg8 + g2b[0]);
    }
    int ks = t >> 7, c = t & 127;
    float a0 = 0.f, a1 = 0.f;
    const float* W  = Wo + (size_t)(ks * 256) * 128 + c;
    const float* x0 = xr[0] + ks * 256;
    const float* x1 = xr[1] + ks * 256;
    #pragma unroll 8
    for (int i = 0; i < 256; i++) { float w = W[(size_t)i * 128]; a0 += x0[i] * w; a1 += x1[i] * w; }
    part[ks][0][c] = a0;
    part[ks][1][c] = a1;
    __syncthreads();
    if (t < 256) {
        int r = t >> 7, cc = t & 127;
        float a = 0.f;
        #pragma unroll
        for (int k2 = 0; k2 < 8; k2++) a += part[k2][r][cc];
        Wh2[(n0 + r) * 128 + cc] = a;
        float ps = wave_sum(a * aos[cc]);
        float pd = wave_sum(a * aod[cc]);
        if ((t & 63) == 0) { rs[t >> 6] = ps; rd[t >> 6] = pd; }
    }
    __syncthreads();
    if (t == 0) { es2[n0] = rs[0] + rs[1]; ed2[n0] = rd[0] + rd[1]; }
    if (t == 1) { es2[n0 + 1] = rs[2] + rs[3]; ed2[n0 + 1] = rd[2] + rd[3]; }
}

// ---------------- K_fin: attn2 (b 0..255) | wsum2p (b 256..319) [R15-proven] ----------------
// grid 320, block 256
__global__ void k_fin(const int* __restrict__ winner, const float* __restrict__ d2,
                      const float* __restrict__ es2, const float* __restrict__ ed2,
                      const float* __restrict__ Wh2, const float* __restrict__ gate2,
                      const float* __restrict__ x1p,
                      float* __restrict__ part2, float* __restrict__ hout2) {
    int b = blockIdx.x, t = threadIdx.x;
    if (b < 256) {
        int s = b, w = t >> 6, l = t & 63;
        __shared__ float mx[4], sm[4], at[256], part[2][128];
        int win = winner[s * 256 + t];
        float e;
        if (win >= 0) e = lrelu(es2[s] + ed2[t] + d2[win]);
        else e = NEGF;
        float m = wave_max(e);
        if (l == 0) mx[w] = m;
        __syncthreads();
        m = fmaxf(fmaxf(mx[0], mx[1]), fmaxf(mx[2], mx[3]));
        float p = expf(e - m);
        float Z = wave_sum(p);
        if (l == 0) sm[w] = Z;
        __syncthreads();
        Z = sm[0] + sm[1] + sm[2] + sm[3];
        at[t] = p / Z;
        __syncthreads();
        int c = t & 127, hf = t >> 7;
        float acc = 0.f;
        for (int d = hf * 128; d < hf * 128 + 128; d++)
            acc += at[d] * Wh2[d * 128 + c];
        part[hf][c] = acc;
        __syncthreads();
        if (t < 128) hout2[s * 128 + t] = part[0][t] + part[1][t];   // concat=False: no elu
    } else {
        int tile = b - 256;
        int cb = tile >> 3, nb = tile & 7;
        __shared__ float mx2[4], sm2[4], al[256];
        int w = t >> 6, l = t & 63;
        float g = gate2[t];
        float m = wave_max(g);
        if (l == 0) mx2[w] = m;
        __syncthreads();
        m = fmaxf(fmaxf(mx2[0], mx2[1]), fmaxf(mx2[2], mx2[3]));
        float p = expf(g - m);
        float Z = wave_sum(p);
        if (l == 0) sm2[w] = Z;
        __syncthreads();
        Z = sm2[0] + sm2[1] + sm2[2] + sm2[3];
        al[t] = p / Z;
        __syncthreads();
        int c = cb * 256 + t;
        int n0 = nb * 32;
        float acc = 0.f;
        #pragma unroll 8
        for (int n = n0; n < n0 + 32; n++) acc += al[n] * x1p[(size_t)n * 2048 + c];
        part2[nb * 2048 + c] = acc;
    }
}

// ---------------- K_tail: pool2+gate3+gattn3 (b 0) | wsumr (b 1..9) [R15-proven] ----------------
// grid 10, block 512
__global__ void k_tail(const float* __restrict__ hout2, const float* __restrict__ Wp,
                       const float* __restrict__ bp, const float* __restrict__ g3W,
                       const float* __restrict__ g3b, const float* __restrict__ part1,
                       const float* __restrict__ part2, float* __restrict__ out) {
    int t = threadIdx.x, w = t >> 6, l = t & 63;
    if (blockIdx.x > 0) {
        int rb = blockIdx.x - 1;
        if (rb == 0) {
            if (t < 64) {
                float o = 0.f;
                #pragma unroll
                for (int nb = 0; nb < 8; nb++) o += part1[nb * 64 + t];
                out[t] = o;
            }
        } else if (t < 256) {
            int c = (rb - 1) * 256 + t;
            float o = 0.f;
            #pragma unroll
            for (int nb = 0; nb < 8; nb++) o += part2[nb * 2048 + c];
            out[64 + c] = o;
        }
        return;
    }
    __shared__ float x2s[128][129];
    __shared__ float gt[128];
    __shared__ float mx[2], sm[2], al[128], part[4][128];
    float bpv = bp[0], g3bv = g3b[0];
    for (int rr = 0; rr < 16; rr++) {
        int k = w * 16 + rr;
        float a0  = hout2[(size_t)(2 * k) * 128 + l];
        float a0b = hout2[(size_t)(2 * k) * 128 + 64 + l];
        float a1  = hout2[(size_t)(2 * k + 1) * 128 + l];
        float a1b = hout2[(size_t)(2 * k + 1) * 128 + 64 + l];
        float p = a0 * Wp[l] + a0b * Wp[64 + l] + a1 * Wp[128 + l] + a1b * Wp[192 + l];
        p = wave_sum(p);
        float sc = sigm(p + bpv);
        float v  = (a0 + a1) * sc;
        float vb = (a0b + a1b) * sc;
        x2s[k][l] = v;
        x2s[k][64 + l] = vb;
        float g = wave_sum(v * g3W[l] + vb * g3W[64 + l]);
        if (l == 0) gt[k] = sigm(g + g3bv);
    }
    __syncthreads();
    if (t < 128) {
        float g = gt[t];
        float m = wave_max(g);
        if (l == 0) mx[w] = m;
    }
    __syncthreads();
    if (t < 128) {
        float g = gt[t];
        float m = fmaxf(mx[0], mx[1]);
        float p = expf(g - m);
        float Z = wave_sum(p);
        if (l == 0) sm[w] = Z;
        al[t] = p;
    }
    __syncthreads();
    float invZ = 1.f / (sm[0] + sm[1]);
    int q = t >> 7, c = t & 127;
    float acc = 0.f;
    for (int n = q * 32; n < q * 32 + 32; n++) acc += al[n] * x2s[n][c];
    part[q][c] = acc * invZ;
    __syncthreads();
    if (t < 128) out[2112 + t] = part[0][t] + part[1][t] + part[2][t] + part[3][t];
}

extern "C" void kernel_launch(void* const* d_in, const int* in_sizes, int n_in,
                              void* d_out, int out_size, void* d_ws, size_t ws_size,
                              hipStream_t stream) {
    const float* feat  = (const float*)d_in[0];
    const int*   eidx  = (const int*)d_in[1];
    const float* eattr = (const float*)d_in[2];
    const float* adj   = (const float*)d_in[3];
    const float* n2n   = (const float*)d_in[4];
    const float* Wsn   = (const float*)d_in[5];
    const float* asn   = (const float*)d_in[6];
    const float* Wg    = (const float*)d_in[7];
    const float* Weg   = (const float*)d_in[8];
    const float* asrc  = (const float*)d_in[9];
    const float* adst  = (const float*)d_in[10];
    const float* aedge = (const float*)d_in[11];
    const float* Wp1   = (const float*)d_in[12];
    const float* bp1   = (const float*)d_in[13];
    const float* Wo    = (const float*)d_in[14];
    const float* Weo   = (const float*)d_in[15];
    const float* aos   = (const float*)d_in[16];
    const float* aod   = (const float*)d_in[17];
    const float* aoe   = (const float*)d_in[18];
    const float* Wp2   = (const float*)d_in[19];
    const float* bp2   = (const float*)d_in[20];
    const float* g1W   = (const float*)d_in[21];
    const float* g1b   = (const float*)d_in[22];
    const float* g2W   = (const float*)d_in[23];
    const float* g2b   = (const float*)d_in[24];
    const float* g3W   = (const float*)d_in[25];
    const float* g3b   = (const float*)d_in[26];
    float* out = (float*)d_out;

    char* ws = (char*)d_ws;
    float* h      = (float*)(ws + 0x0000000);   // 128KB
    float* z      = (float*)(ws + 0x0020000);   // 2MB
    float* ve1    = (float*)(ws + 0x0430000);   // 4KB
    float* ve2    = (float*)(ws + 0x0431000);   // 8KB
    float* gate1  = (float*)(ws + 0x0433000);   // 2KB
    float* gate2  = (float*)(ws + 0x0434000);   // 1KB
    float* vs1    = (float*)(ws + 0x0436000);   // 4KB
    float* vd1    = (float*)(ws + 0x0438000);   // 4KB
    float* es1    = (float*)(ws + 0x0440000);   // 32KB
    float* ed1    = (float*)(ws + 0x0448000);   // 32KB
    float* d2     = (float*)(ws + 0x1840000);   // 16KB
    float* x1p    = (float*)(ws + 0x1850000);   // 2MB
    int*   winner = (int*)  (ws + 0x1A50000);   // 256KB
    float* Wh2    = (float*)(ws + 0x1A90000);   // 128KB
    float* es2    = (float*)(ws + 0x1AB0000);   // 1KB
    float* ed2    = (float*)(ws + 0x1AB1000);   // 1KB
    float* hout2  = (float*)(ws + 0x1AB2000);   // 128KB
    float* part2  = (float*)(ws + 0x1AE2000);   // 64KB
    float* part1  = (float*)(ws + 0x1AF2000);   // 2KB

    k_setup  <<<176, 256, 0, stream>>>(Wg, Weg, asrc, adst, aedge, Weo, aoe,
                                       feat, Wsn, asn, g1W, g1b,
                                       vs1, vd1, ve1, ve2, winner, h, gate1);
    k_mid    <<<32, 512, 0, stream>>>(h, gate1, vs1, vd1, eidx, part1, es1, ed1, winner);
    k_attn_ze<<<1024, 512, 0, stream>>>(adj, n2n, h, ve1, es1, ed1, eattr, Weg, ve2, z, d2);
    k_big2p  <<<128, 1024, 0, stream>>>(z, Wg, Wp1, bp1, g2W, g2b, Wo, aos, aod,
                                        x1p, gate2, Wh2, es2, ed2);
    k_fin    <<<320, 256, 0, stream>>>(winner, d2, es2, ed2, Wh2, gate2, x1p, part2, hout2);
    k_tail   <<<10, 512, 0, stream>>>(hout2, Wp2, bp2, g3W, g3b, part1, part2, out);
}

// Round 18
// 117.350 us; speedup vs baseline: 1.3914x; 1.0348x over previous
//
#include <hip/hip_runtime.h>
#include <hip/hip_bf16.h>

__device__ __forceinline__ float sigm(float x) { return 1.f / (1.f + expf(-x)); }
__device__ __forceinline__ float lrelu(float x) { return x > 0.f ? x : 0.2f * x; }
__device__ __forceinline__ float eluf(float x) { return x > 0.f ? x : expf(x) - 1.f; }

#define NEGF (-9e15f)
#define MAXD 40   // deg ~ Binom(4096,1/512): mean 8, sigma 2.8 -> P(deg>40) ~ 1e-28

__device__ __forceinline__ float wave_sum(float v) {
    #pragma unroll
    for (int off = 32; off >= 1; off >>= 1) v += __shfl_xor(v, off);
    return v;
}
__device__ __forceinline__ float wave_max(float v) {
    #pragma unroll
    for (int off = 32; off >= 1; off >>= 1) v = fmaxf(v, __shfl_xor(v, off));
    return v;
}
__device__ __forceinline__ float half_sum(float v) {
    #pragma unroll
    for (int off = 16; off >= 1; off >>= 1) v += __shfl_xor(v, off);
    return v;
}
__device__ __forceinline__ float half_max(float v) {
    #pragma unroll
    for (int off = 16; off >= 1; off >>= 1) v = fmaxf(v, __shfl_xor(v, off));
    return v;
}

// ---------------- K_setup ----------------
// grid 176, block 256
__global__ void k_setup(const float* __restrict__ Wg, const float* __restrict__ Weg,
                        const float* __restrict__ asrc, const float* __restrict__ adst,
                        const float* __restrict__ aedge, const float* __restrict__ Weo,
                        const float* __restrict__ aoe,
                        const float* __restrict__ feat, const float* __restrict__ Wsn,
                        const float* __restrict__ asn, const float* __restrict__ g1W,
                        const float* __restrict__ g1b,
                        float* __restrict__ vs1, float* __restrict__ vd1, float* __restrict__ ve1,
                        float* __restrict__ ve2, int* __restrict__ winner,
                        float* __restrict__ h, float* __restrict__ gate1) {
    int b = blockIdx.x, t = threadIdx.x, w = t >> 6, l = t & 63;
    __shared__ float fr[4][64];
    if (b < 16) {
        int hd = b;
        float s0 = asrc[hd * 128 + l],  s1 = asrc[hd * 128 + 64 + l];
        float d0 = adst[hd * 128 + l],  d1 = adst[hd * 128 + 64 + l];
        float e0 = aedge[hd * 128 + l], e1 = aedge[hd * 128 + 64 + l];
        for (int i = w; i < 64; i += 4) {
            const float* Wr = Wg  + ((size_t)hd * 64 + i) * 128;
            const float* Er = Weg + ((size_t)hd * 64 + i) * 128;
            float w1 = Wr[l], w2 = Wr[64 + l];
            float q1 = Er[l], q2 = Er[64 + l];
            float pS = wave_sum(w1 * s0 + w2 * s1);
            float pD = wave_sum(w1 * d0 + w2 * d1);
            float pE = wave_sum(q1 * e0 + q2 * e1);
            if (l == 0) { vs1[hd * 64 + i] = pS; vd1[hd * 64 + i] = pD; ve1[hd * 64 + i] = pE; }
        }
    } else if (b < 32) {
        int base = (b - 16) * 128;
        float a0 = aoe[l], a1 = aoe[64 + l];
        for (int k = 0; k < 32; k++) {
            int c = base + w * 32 + k;
            const float* Wr = Weo + (size_t)c * 128;
            float p = wave_sum(Wr[l] * a0 + Wr[64 + l] * a1);
            if (l == 0) ve2[c] = p;
        }
    } else if (b < 48) {
        int base = (b - 32) * 4096;
        #pragma unroll
        for (int k = 0; k < 16; k++) winner[base + k * 256 + t] = -1;
    } else {
        int n = (b - 48) * 4 + w;
        fr[w][l] = feat[n * 64 + l];
        __syncthreads();
        float acc = 0.f;
        #pragma unroll 8
        for (int i = 0; i < 64; i++) acc += fr[w][i] * Wsn[i * 64 + l];
        float p = wave_sum(acc * asn[l]);
        float coef = sigm(lrelu(p));
        float hv = eluf(coef * acc);
        h[n * 64 + l] = hv;
        float g = wave_sum(hv * g1W[l]);
        if (l == 0) gate1[n] = sigm(g + g1b[0]);
    }
}

// ---------------- K_attn_ze: attn_z (b 0..511, es/ed inline) | edot (b 512..1023)
//                  | wsum1p (b 1024..1031) | scatter (b 1032..1039) ----------------
// grid 1040, block 512
__global__ void k_attn_ze(const float* __restrict__ adj, const float* __restrict__ n2n,
                          const float* __restrict__ h, const float* __restrict__ ve1,
                          const float* __restrict__ vs1, const float* __restrict__ vd1,
                          const float* __restrict__ eattr, const float* __restrict__ Weg,
                          const float* __restrict__ ve2, const float* __restrict__ gate1,
                          const int* __restrict__ ei,
                          float* __restrict__ z, float* __restrict__ d2,
                          float* __restrict__ part1, int* __restrict__ winner) {
    int b = blockIdx.x, t = threadIdx.x, w = t >> 6, l = t & 63;
    if (b >= 1032) {
        // scatter: last-wins winner edge per (src/2, dst/2)
        int e = (b - 1032) * 512 + t;
        int s = ei[e] >> 1, d = ei[4096 + e] >> 1;
        atomicMax(&winner[s * 256 + d], e);
        return;
    }
    if (b >= 1024) {
        // wsum1p [R15-proven body]
        int nb = b - 1024;
        __shared__ float mx[8], sm[8], al[512], pt[8][64];
        float g = gate1[t];
        float m = wave_max(g);
        if (l == 0) mx[w] = m;
        __syncthreads();
        m = mx[0];
        #pragma unroll
        for (int i = 1; i < 8; i++) m = fmaxf(m, mx[i]);
        float p = expf(g - m);
        float Z = wave_sum(p);
        if (l == 0) sm[w] = Z;
        __syncthreads();
        Z = 0.f;
        #pragma unroll
        for (int i = 0; i < 8; i++) Z += sm[i];
        al[t] = p / Z;
        __syncthreads();
        int r0 = nb * 64 + w * 8;
        float acc = 0.f;
        #pragma unroll
        for (int r = 0; r < 8; r++) acc += al[r0 + r] * h[(r0 + r) * 64 + l];
        pt[w][l] = acc;
        __syncthreads();
        if (t < 64) {
            float o = 0.f;
            #pragma unroll
            for (int q = 0; q < 8; q++) o += pt[q][t];
            part1[nb * 64 + t] = o;
        }
        return;
    }
    if (b >= 512) {
        // edot [R14-proven]: 8 edges/block; float4 acc[8] = 32 regs
        int e0 = (b - 512) * 8;
        int hd = t >> 5, q = t & 31;
        __shared__ float ea[8][64];
        __shared__ float sd2[8][8];
        ea[t >> 6][t & 63] = eattr[(size_t)(e0 + (t >> 6)) * 64 + (t & 63)];
        __syncthreads();
        float4 acc[8];
        #pragma unroll
        for (int r = 0; r < 8; r++) acc[r] = make_float4(0.f, 0.f, 0.f, 0.f);
        const float4* W4 = (const float4*)Weg + (size_t)hd * 2048 + q;
        #pragma unroll 4
        for (int i = 0; i < 64; i++) {
            float4 wv = W4[i * 32];
            #pragma unroll
            for (int r = 0; r < 8; r++) {
                float a = ea[r][i];
                acc[r].x += a * wv.x; acc[r].y += a * wv.y;
                acc[r].z += a * wv.z; acc[r].w += a * wv.w;
            }
        }
        float4 v2 = ((const float4*)ve2)[hd * 32 + q];
        #pragma unroll
        for (int r = 0; r < 8; r++) {
            float p = eluf(acc[r].x) * v2.x + eluf(acc[r].y) * v2.y
                    + eluf(acc[r].z) * v2.z + eluf(acc[r].w) * v2.w;
            p = wave_sum(p);
            if (l == 0) sd2[r][w] = p;
        }
        __syncthreads();
        if (t < 8) {
            float s8 = 0.f;
            #pragma unroll
            for (int k = 0; k < 8; k++) s8 += sd2[t][k];
            d2[e0 + t] = s8;
        }
        return;
    }
    // attn: es/ed computed inline (R7-proven math) + R14 wave-parallel softmax
    int s = b;
    __shared__ float vlT[64][17], vsT[64][17], vdT[64][17];
    __shared__ float hsr[64];
    __shared__ float hrow[MAXD][65], nrow[MAXD][65];
    __shared__ float eh[16][48], ah[16][48];
    __shared__ float es_s[16];
    __shared__ int dlist[MAXD];
    __shared__ int wbase[8];
    __shared__ int nnz_s;
    __shared__ float part[8][64];

    for (int idx = t; idx < 1024; idx += 512) {
        int i = idx & 63, hd = idx >> 6;
        vlT[i][hd] = ve1[hd * 64 + i];
        vsT[i][hd] = vs1[hd * 64 + i];
        vdT[i][hd] = vd1[hd * 64 + i];
    }
    if (t < 64) hsr[t] = h[s * 64 + t];
    float a = adj[s * 512 + t];
    unsigned long long mask = __ballot(a > 0.f);
    if (l == 0) wbase[w] = __popcll(mask);
    __syncthreads();
    if (t == 0) {
        int run = 0;
        #pragma unroll
        for (int i = 0; i < 8; i++) { int c = wbase[i]; wbase[i] = run; run += c; }
        nnz_s = run;
    }
    __syncthreads();
    if (a > 0.f) {
        int slot = wbase[w] + __popcll(mask & ((1ULL << l) - 1ULL));
        if (slot < MAXD) dlist[slot] = t;
    }
    __syncthreads();
    int nnz = min(nnz_s, MAXD);

    if (nnz == 0) {
        int i = t & 63, q = t >> 6;
        float acc = 0.f;
        for (int d = q * 64; d < q * 64 + 64; d++) acc += h[d * 64 + i];
        part[q][i] = acc;
        __syncthreads();
        if (t < 64) {
            float sum = 0.f;
            #pragma unroll
            for (int q2 = 0; q2 < 8; q2++) sum += part[q2][t];
            float v = sum * (1.f / 512.f);
            for (int hd = 0; hd < 16; hd++) z[(size_t)s * 1024 + hd * 64 + t] = v;
        }
        return;
    }

    for (int base = 0; base < nnz; base += 8) {
        int j = base + (t >> 6);
        if (j < nnz) {
            int d = dlist[j];
            hrow[j][l] = h[d * 64 + l];
            nrow[j][l] = n2n[((size_t)s * 512 + d) * 64 + l];
        }
    }
    if (t < 16) {   // es[hd] = h[s]·vs1[hd]
        float acc = 0.f;
        for (int i = 0; i < 64; i++) acc += hsr[i] * vsT[i][t];
        es_s[t] = acc;
    }
    __syncthreads();
    // logits: e[hd][j] = lrelu(es + hrow[j]·vd1[hd] + nrow[j]·ve1[hd])
    for (int jb = 0; jb < nnz; jb += 32) {
        int j = jb + (t >> 4), hd = t & 15;
        if (j < nnz) {
            float ee = 0.f, edv = 0.f;
            #pragma unroll 8
            for (int i = 0; i < 64; i++) {
                ee  += nrow[j][i] * vlT[i][hd];
                edv += hrow[j][i] * vdT[i][hd];
            }
            eh[hd][j] = lrelu(es_s[hd] + edv + ee);
        }
    }
    __syncthreads();
    {
        int hd = t >> 5, lane32 = t & 31;
        float v0 = (lane32 < nnz) ? eh[hd][lane32] : -1e30f;
        float v1 = (lane32 + 32 < nnz) ? eh[hd][lane32 + 32] : -1e30f;
        float m = half_max(fmaxf(v0, v1));
        float p0 = (lane32 < nnz) ? expf(v0 - m) : 0.f;
        float p1 = (lane32 + 32 < nnz) ? expf(v1 - m) : 0.f;
        float Z = half_sum(p0 + p1);
        float inv = 1.f / Z;
        if (lane32 < nnz) ah[hd][lane32] = p0 * inv;
        if (lane32 + 32 < nnz) ah[hd][lane32 + 32] = p1 * inv;
    }
    __syncthreads();
    int hd = t >> 5, i0 = t & 31;
    float a0 = 0.f, a1 = 0.f;
    for (int j = 0; j < nnz; j++) {
        float aj = ah[hd][j];
        a0 += aj * hrow[j][i0];
        a1 += aj * hrow[j][i0 + 32];
    }
    z[(size_t)s * 1024 + hd * 64 + i0]      = a0;
    z[(size_t)s * 1024 + hd * 64 + i0 + 32] = a1;
}

// ---------------- K_big2p: hout(z@Wg) + pool1 + gate2 + wh2 fused [R17-proven] ----------------
// grid 128, block 1024
__global__ void k_big2p(const float* __restrict__ z, const float* __restrict__ Wg,
                        const float* __restrict__ Wp1, const float* __restrict__ bp1,
                        const float* __restrict__ g2W, const float* __restrict__ g2b,
                        const float* __restrict__ Wo,
                        const float* __restrict__ aos, const float* __restrict__ aod,
                        float* __restrict__ x1p, float* __restrict__ gate2,
                        float* __restrict__ Wh2, float* __restrict__ es2, float* __restrict__ ed2) {
    int b = blockIdx.x, t = threadIdx.x;
    __shared__ __align__(16) char smem[57600];
    float (*zt)[1024]    = reinterpret_cast<float(*)[1024]>(smem);
    float (*xr)[2048]    = reinterpret_cast<float(*)[2048]>(smem);
    float (*hs)[2048]    = reinterpret_cast<float(*)[2048]>(smem + 16384);
    float (*part)[2][128]= reinterpret_cast<float(*)[2][128]>(smem + 49152);
    float *red = reinterpret_cast<float*>(smem + 57344);
    float *rs  = reinterpret_cast<float*>(smem + 57408);
    float *rd  = reinterpret_cast<float*>(smem + 57424);
    int n0 = 2 * b;
    for (int idx = t; idx < 4096; idx += 1024)
        zt[idx >> 10][idx & 1023] = z[(size_t)(4 * b) * 1024 + idx];
    __syncthreads();
    {
        int c = t & 127, g8 = t >> 7;
        #pragma unroll
        for (int it = 0; it < 2; it++) {
            int hd = g8 + 8 * it;
            const float* W = Wg + (size_t)hd * 8192 + c;
            const float* z0 = &zt[0][hd * 64];
            const float* z1 = &zt[1][hd * 64];
            const float* z2 = &zt[2][hd * 64];
            const float* z3 = &zt[3][hd * 64];
            float a0 = 0.f, a1 = 0.f, a2 = 0.f, a3 = 0.f;
            #pragma unroll 8
            for (int i = 0; i < 64; i++) {
                float wv = W[(size_t)i * 128];
                a0 += z0[i] * wv; a1 += z1[i] * wv;
                a2 += z2[i] * wv; a3 += z3[i] * wv;
            }
            hs[0][hd * 128 + c] = eluf(a0);
            hs[1][hd * 128 + c] = eluf(a1);
            hs[2][hd * 128 + c] = eluf(a2);
            hs[3][hd * 128 + c] = eluf(a3);
        }
    }
    __syncthreads();
    int g = t >> 9, tt = t & 511;
    float p = 0.f;
    for (int f = tt; f < 2048; f += 512)
        p += hs[2 * g][f] * Wp1[f] + hs[2 * g + 1][f] * Wp1[2048 + f];
    p = wave_sum(p);
    if ((t & 63) == 0) red[t >> 6] = p;
    __syncthreads();
    float s8 = 0.f;
    #pragma unroll
    for (int k2 = 0; k2 < 8; k2++) s8 += red[g * 8 + k2];
    float sc = sigm(s8 + bp1[0]);
    __syncthreads();
    float pg = 0.f;
    for (int f = tt; f < 2048; f += 512) {
        float v = (hs[2 * g][f] + hs[2 * g + 1][f]) * sc;
        xr[g][f] = v;
        x1p[(size_t)(n0 + g) * 2048 + f] = v;
        pg += v * g2W[f];
    }
    pg = wave_sum(pg);
    if ((t & 63) == 0) red[t >> 6] = pg;
    __syncthreads();
    if (t == 0 || t == 512) {
        float sg8 = 0.f;
        #pragma unroll
        for (int k2 = 0; k2 < 8; k2++) sg8 += red[g * 8 + k2];
        gate2[n0 + g] = sigm(sg8 + g2b[0]);
    }
    int ks = t >> 7, c = t & 127;
    float a0 = 0.f, a1 = 0.f;
    const float* W  = Wo + (size_t)(ks * 256) * 128 + c;
    const float* x0 = xr[0] + ks * 256;
    const float* x1 = xr[1] + ks * 256;
    #pragma unroll 8
    for (int i = 0; i < 256; i++) { float w = W[(size_t)i * 128]; a0 += x0[i] * w; a1 += x1[i] * w; }
    part[ks][0][c] = a0;
    part[ks][1][c] = a1;
    __syncthreads();
    if (t < 256) {
        int r = t >> 7, cc = t & 127;
        float a = 0.f;
        #pragma unroll
        for (int k2 = 0; k2 < 8; k2++) a += part[k2][r][cc];
        Wh2[(n0 + r) * 128 + cc] = a;
        float ps = wave_sum(a * aos[cc]);
        float pd = wave_sum(a * aod[cc]);
        if ((t & 63) == 0) { rs[t >> 6] = ps; rd[t >> 6] = pd; }
    }
    __syncthreads();
    if (t == 0) { es2[n0] = rs[0] + rs[1]; ed2[n0] = rd[0] + rd[1]; }
    if (t == 1) { es2[n0 + 1] = rs[2] + rs[3]; ed2[n0 + 1] = rd[2] + rd[3]; }
}

// ---------------- K_fin: attn2 (b 0..255) | wsum2p (b 256..319) [R15-proven] ----------------
// grid 320, block 256
__global__ void k_fin(const int* __restrict__ winner, const float* __restrict__ d2,
                      const float* __restrict__ es2, const float* __restrict__ ed2,
                      const float* __restrict__ Wh2, const float* __restrict__ gate2,
                      const float* __restrict__ x1p,
                      float* __restrict__ part2, float* __restrict__ hout2) {
    int b = blockIdx.x, t = threadIdx.x;
    if (b < 256) {
        int s = b, w = t >> 6, l = t & 63;
        __shared__ float mx[4], sm[4], at[256], part[2][128];
        int win = winner[s * 256 + t];
        float e;
        if (win >= 0) e = lrelu(es2[s] + ed2[t] + d2[win]);
        else e = NEGF;
        float m = wave_max(e);
        if (l == 0) mx[w] = m;
        __syncthreads();
        m = fmaxf(fmaxf(mx[0], mx[1]), fmaxf(mx[2], mx[3]));
        float p = expf(e - m);
        float Z = wave_sum(p);
        if (l == 0) sm[w] = Z;
        __syncthreads();
        Z = sm[0] + sm[1] + sm[2] + sm[3];
        at[t] = p / Z;
        __syncthreads();
        int c = t & 127, hf = t >> 7;
        float acc = 0.f;
        for (int d = hf * 128; d < hf * 128 + 128; d++)
            acc += at[d] * Wh2[d * 128 + c];
        part[hf][c] = acc;
        __syncthreads();
        if (t < 128) hout2[s * 128 + t] = part[0][t] + part[1][t];   // concat=False: no elu
    } else {
        int tile = b - 256;
        int cb = tile >> 3, nb = tile & 7;
        __shared__ float mx2[4], sm2[4], al[256];
        int w = t >> 6, l = t & 63;
        float g = gate2[t];
        float m = wave_max(g);
        if (l == 0) mx2[w] = m;
        __syncthreads();
        m = fmaxf(fmaxf(mx2[0], mx2[1]), fmaxf(mx2[2], mx2[3]));
        float p = expf(g - m);
        float Z = wave_sum(p);
        if (l == 0) sm2[w] = Z;
        __syncthreads();
        Z = sm2[0] + sm2[1] + sm2[2] + sm2[3];
        al[t] = p / Z;
        __syncthreads();
        int c = cb * 256 + t;
        int n0 = nb * 32;
        float acc = 0.f;
        #pragma unroll 8
        for (int n = n0; n < n0 + 32; n++) acc += al[n] * x1p[(size_t)n * 2048 + c];
        part2[nb * 2048 + c] = acc;
    }
}

// ---------------- K_tail: pool2+gate3+gattn3 (b 0) | wsumr (b 1..9) [R15-proven] ----------------
// grid 10, block 512
__global__ void k_tail(const float* __restrict__ hout2, const float* __restrict__ Wp,
                       const float* __restrict__ bp, const float* __restrict__ g3W,
                       const float* __restrict__ g3b, const float* __restrict__ part1,
                       const float* __restrict__ part2, float* __restrict__ out) {
    int t = threadIdx.x, w = t >> 6, l = t & 63;
    if (blockIdx.x > 0) {
        int rb = blockIdx.x - 1;
        if (rb == 0) {
            if (t < 64) {
                float o = 0.f;
                #pragma unroll
                for (int nb = 0; nb < 8; nb++) o += part1[nb * 64 + t];
                out[t] = o;
            }
        } else if (t < 256) {
            int c = (rb - 1) * 256 + t;
            float o = 0.f;
            #pragma unroll
            for (int nb = 0; nb < 8; nb++) o += part2[nb * 2048 + c];
            out[64 + c] = o;
        }
        return;
    }
    __shared__ float x2s[128][129];
    __shared__ float gt[128];
    __shared__ float mx[2], sm[2], al[128], part[4][128];
    float bpv = bp[0], g3bv = g3b[0];
    for (int rr = 0; rr < 16; rr++) {
        int k = w * 16 + rr;
        float a0  = hout2[(size_t)(2 * k) * 128 + l];
        float a0b = hout2[(size_t)(2 * k) * 128 + 64 + l];
        float a1  = hout2[(size_t)(2 * k + 1) * 128 + l];
        float a1b = hout2[(size_t)(2 * k + 1) * 128 + 64 + l];
        float p = a0 * Wp[l] + a0b * Wp[64 + l] + a1 * Wp[128 + l] + a1b * Wp[192 + l];
        p = wave_sum(p);
        float sc = sigm(p + bpv);
        float v  = (a0 + a1) * sc;
        float vb = (a0b + a1b) * sc;
        x2s[k][l] = v;
        x2s[k][64 + l] = vb;
        float g = wave_sum(v * g3W[l] + vb * g3W[64 + l]);
        if (l == 0) gt[k] = sigm(g + g3bv);
    }
    __syncthreads();
    if (t < 128) {
        float g = gt[t];
        float m = wave_max(g);
        if (l == 0) mx[w] = m;
    }
    __syncthreads();
    if (t < 128) {
        float g = gt[t];
        float m = fmaxf(mx[0], mx[1]);
        float p = expf(g - m);
        float Z = wave_sum(p);
        if (l == 0) sm[w] = Z;
        al[t] = p;
    }
    __syncthreads();
    float invZ = 1.f / (sm[0] + sm[1]);
    int q = t >> 7, c = t & 127;
    float acc = 0.f;
    for (int n = q * 32; n < q * 32 + 32; n++) acc += al[n] * x2s[n][c];
    part[q][c] = acc * invZ;
    __syncthreads();
    if (t < 128) out[2112 + t] = part[0][t] + part[1][t] + part[2][t] + part[3][t];
}

extern "C" void kernel_launch(void* const* d_in, const int* in_sizes, int n_in,
                              void* d_out, int out_size, void* d_ws, size_t ws_size,
                              hipStream_t stream) {
    const float* feat  = (const float*)d_in[0];
    const int*   eidx  = (const int*)d_in[1];
    const float* eattr = (const float*)d_in[2];
    const float* adj   = (const float*)d_in[3];
    const float* n2n   = (const float*)d_in[4];
    const float* Wsn   = (const float*)d_in[5];
    const float* asn   = (const float*)d_in[6];
    const float* Wg    = (const float*)d_in[7];
    const float* Weg   = (const float*)d_in[8];
    const float* asrc  = (const float*)d_in[9];
    const float* adst  = (const float*)d_in[10];
    const float* aedge = (const float*)d_in[11];
    const float* Wp1   = (const float*)d_in[12];
    const float* bp1   = (const float*)d_in[13];
    const float* Wo    = (const float*)d_in[14];
    const float* Weo   = (const float*)d_in[15];
    const float* aos   = (const float*)d_in[16];
    const float* aod   = (const float*)d_in[17];
    const float* aoe   = (const float*)d_in[18];
    const float* Wp2   = (const float*)d_in[19];
    const float* bp2   = (const float*)d_in[20];
    const float* g1W   = (const float*)d_in[21];
    const float* g1b   = (const float*)d_in[22];
    const float* g2W   = (const float*)d_in[23];
    const float* g2b   = (const float*)d_in[24];
    const float* g3W   = (const float*)d_in[25];
    const float* g3b   = (const float*)d_in[26];
    float* out = (float*)d_out;

    char* ws = (char*)d_ws;
    float* h      = (float*)(ws + 0x0000000);   // 128KB
    float* z      = (float*)(ws + 0x0020000);   // 2MB
    float* ve1    = (float*)(ws + 0x0430000);   // 4KB
    float* ve2    = (float*)(ws + 0x0431000);   // 8KB
    float* gate1  = (float*)(ws + 0x0433000);   // 2KB
    float* gate2  = (float*)(ws + 0x0434000);   // 1KB
    float* vs1    = (float*)(ws + 0x0436000);   // 4KB
    float* vd1    = (float*)(ws + 0x0438000);   // 4KB
    float* d2     = (float*)(ws + 0x1840000);   // 16KB
    float* x1p    = (float*)(ws + 0x1850000);   // 2MB
    int*   winner = (int*)  (ws + 0x1A50000);   // 256KB
    float* Wh2    = (float*)(ws + 0x1A90000);   // 128KB
    float* es2    = (float*)(ws + 0x1AB0000);   // 1KB
    float* ed2    = (float*)(ws + 0x1AB1000);   // 1KB
    float* hout2  = (float*)(ws + 0x1AB2000);   // 128KB
    float* part2  = (float*)(ws + 0x1AE2000);   // 64KB
    float* part1  = (float*)(ws + 0x1AF2000);   // 2KB

    k_setup  <<<176, 256, 0, stream>>>(Wg, Weg, asrc, adst, aedge, Weo, aoe,
                                       feat, Wsn, asn, g1W, g1b,
                                       vs1, vd1, ve1, ve2, winner, h, gate1);
    k_attn_ze<<<1040, 512, 0, stream>>>(adj, n2n, h, ve1, vs1, vd1, eattr, Weg, ve2,
                                        gate1, eidx, z, d2, part1, winner);
    k_big2p  <<<128, 1024, 0, stream>>>(z, Wg, Wp1, bp1, g2W, g2b, Wo, aos, aod,
                                        x1p, gate2, Wh2, es2, ed2);
    k_fin    <<<320, 256, 0, stream>>>(winner, d2, es2, ed2, Wh2, gate2, x1p, part2, hout2);
    k_tail   <<<10, 512, 0, stream>>>(hout2, Wp2, bp2, g3W, g3b, part1, part2, out);
}

// Round 20
// 116.465 us; speedup vs baseline: 1.4020x; 1.0076x over previous
//
#include <hip/hip_runtime.h>
#include <hip/hip_bf16.h>

__device__ __forceinline__ float sigm(float x) { return 1.f / (1.f + expf(-x)); }
__device__ __forceinline__ float lrelu(float x) { return x > 0.f ? x : 0.2f * x; }
__device__ __forceinline__ float eluf(float x) { return x > 0.f ? x : expf(x) - 1.f; }

#define NEGF (-9e15f)
#define MAXD 40   // deg ~ Binom(4096,1/512): mean 8, sigma 2.8 -> P(deg>40) ~ 1e-28

__device__ __forceinline__ float wave_sum(float v) {
    #pragma unroll
    for (int off = 32; off >= 1; off >>= 1) v += __shfl_xor(v, off);
    return v;
}
__device__ __forceinline__ float wave_max(float v) {
    #pragma unroll
    for (int off = 32; off >= 1; off >>= 1) v = fmaxf(v, __shfl_xor(v, off));
    return v;
}
__device__ __forceinline__ float half_sum(float v) {
    #pragma unroll
    for (int off = 16; off >= 1; off >>= 1) v += __shfl_xor(v, off);
    return v;
}
__device__ __forceinline__ float half_max(float v) {
    #pragma unroll
    for (int off = 16; off >= 1; off >>= 1) v = fmaxf(v, __shfl_xor(v, off));
    return v;
}

// ---------------- K_setup ----------------
// grid 176, block 256
__global__ void k_setup(const float* __restrict__ Wg, const float* __restrict__ Weg,
                        const float* __restrict__ asrc, const float* __restrict__ adst,
                        const float* __restrict__ aedge, const float* __restrict__ Weo,
                        const float* __restrict__ aoe,
                        const float* __restrict__ feat, const float* __restrict__ Wsn,
                        const float* __restrict__ asn, const float* __restrict__ g1W,
                        const float* __restrict__ g1b,
                        float* __restrict__ vs1, float* __restrict__ vd1, float* __restrict__ ve1,
                        float* __restrict__ ve2, int* __restrict__ winner,
                        float* __restrict__ h, float* __restrict__ gate1) {
    int b = blockIdx.x, t = threadIdx.x, w = t >> 6, l = t & 63;
    __shared__ float fr[4][64];
    if (b < 16) {
        int hd = b;
        float s0 = asrc[hd * 128 + l],  s1 = asrc[hd * 128 + 64 + l];
        float d0 = adst[hd * 128 + l],  d1 = adst[hd * 128 + 64 + l];
        float e0 = aedge[hd * 128 + l], e1 = aedge[hd * 128 + 64 + l];
        for (int i = w; i < 64; i += 4) {
            const float* Wr = Wg  + ((size_t)hd * 64 + i) * 128;
            const float* Er = Weg + ((size_t)hd * 64 + i) * 128;
            float w1 = Wr[l], w2 = Wr[64 + l];
            float q1 = Er[l], q2 = Er[64 + l];
            float pS = wave_sum(w1 * s0 + w2 * s1);
            float pD = wave_sum(w1 * d0 + w2 * d1);
            float pE = wave_sum(q1 * e0 + q2 * e1);
            if (l == 0) { vs1[hd * 64 + i] = pS; vd1[hd * 64 + i] = pD; ve1[hd * 64 + i] = pE; }
        }
    } else if (b < 32) {
        int base = (b - 16) * 128;
        float a0 = aoe[l], a1 = aoe[64 + l];
        for (int k = 0; k < 32; k++) {
            int c = base + w * 32 + k;
            const float* Wr = Weo + (size_t)c * 128;
            float p = wave_sum(Wr[l] * a0 + Wr[64 + l] * a1);
            if (l == 0) ve2[c] = p;
        }
    } else if (b < 48) {
        int base = (b - 32) * 4096;
        #pragma unroll
        for (int k = 0; k < 16; k++) winner[base + k * 256 + t] = -1;
    } else {
        int n = (b - 48) * 4 + w;
        fr[w][l] = feat[n * 64 + l];
        __syncthreads();
        float acc = 0.f;
        #pragma unroll 8
        for (int i = 0; i < 64; i++) acc += fr[w][i] * Wsn[i * 64 + l];
        float p = wave_sum(acc * asn[l]);
        float coef = sigm(lrelu(p));
        float hv = eluf(coef * acc);
        h[n * 64 + l] = hv;
        float g = wave_sum(hv * g1W[l]);
        if (l == 0) gate1[n] = sigm(g + g1b[0]);
    }
}

// ---------------- K_attn_ze: attn_z (b 0..511, es/ed inline) | edot (b 512..1023)
//                  | wsum1p (b 1024..1031) | scatter (b 1032..1039) ----------------
// grid 1040, block 512
__global__ void k_attn_ze(const float* __restrict__ adj, const float* __restrict__ n2n,
                          const float* __restrict__ h, const float* __restrict__ ve1,
                          const float* __restrict__ vs1, const float* __restrict__ vd1,
                          const float* __restrict__ eattr, const float* __restrict__ Weg,
                          const float* __restrict__ ve2, const float* __restrict__ gate1,
                          const int* __restrict__ ei,
                          float* __restrict__ z, float* __restrict__ d2,
                          float* __restrict__ part1, int* __restrict__ winner) {
    int b = blockIdx.x, t = threadIdx.x, w = t >> 6, l = t & 63;
    if (b >= 1032) {
        // scatter: last-wins winner edge per (src/2, dst/2)
        int e = (b - 1032) * 512 + t;
        int s = ei[e] >> 1, d = ei[4096 + e] >> 1;
        atomicMax(&winner[s * 256 + d], e);
        return;
    }
    if (b >= 1024) {
        // wsum1p
        int nb = b - 1024;
        __shared__ float mx[8], sm[8], al[512], pt[8][64];
        float g = gate1[t];
        float m = wave_max(g);
        if (l == 0) mx[w] = m;
        __syncthreads();
        m = mx[0];
        #pragma unroll
        for (int i = 1; i < 8; i++) m = fmaxf(m, mx[i]);
        float p = expf(g - m);
        float Z = wave_sum(p);
        if (l == 0) sm[w] = Z;
        __syncthreads();
        Z = 0.f;
        #pragma unroll
        for (int i = 0; i < 8; i++) Z += sm[i];
        al[t] = p / Z;
        __syncthreads();
        int r0 = nb * 64 + w * 8;
        float acc = 0.f;
        #pragma unroll
        for (int r = 0; r < 8; r++) acc += al[r0 + r] * h[(r0 + r) * 64 + l];
        pt[w][l] = acc;
        __syncthreads();
        if (t < 64) {
            float o = 0.f;
            #pragma unroll
            for (int q = 0; q < 8; q++) o += pt[q][t];
            part1[nb * 64 + t] = o;
        }
        return;
    }
    if (b >= 512) {
        // edot: 8 edges/block; float4 acc[8] = 32 regs
        int e0 = (b - 512) * 8;
        int hd = t >> 5, q = t & 31;
        __shared__ float ea[8][64];
        __shared__ float sd2[8][8];
        ea[t >> 6][t & 63] = eattr[(size_t)(e0 + (t >> 6)) * 64 + (t & 63)];
        __syncthreads();
        float4 acc[8];
        #pragma unroll
        for (int r = 0; r < 8; r++) acc[r] = make_float4(0.f, 0.f, 0.f, 0.f);
        const float4* W4 = (const float4*)Weg + (size_t)hd * 2048 + q;
        #pragma unroll 4
        for (int i = 0; i < 64; i++) {
            float4 wv = W4[i * 32];
            #pragma unroll
            for (int r = 0; r < 8; r++) {
                float a = ea[r][i];
                acc[r].x += a * wv.x; acc[r].y += a * wv.y;
                acc[r].z += a * wv.z; acc[r].w += a * wv.w;
            }
        }
        float4 v2 = ((const float4*)ve2)[hd * 32 + q];
        #pragma unroll
        for (int r = 0; r < 8; r++) {
            float p = eluf(acc[r].x) * v2.x + eluf(acc[r].y) * v2.y
                    + eluf(acc[r].z) * v2.z + eluf(acc[r].w) * v2.w;
            p = wave_sum(p);
            if (l == 0) sd2[r][w] = p;
        }
        __syncthreads();
        if (t < 8) {
            float s8 = 0.f;
            #pragma unroll
            for (int k = 0; k < 8; k++) s8 += sd2[t][k];
            d2[e0 + t] = s8;
        }
        return;
    }
    // attn: es/ed computed inline + wave-parallel softmax
    int s = b;
    __shared__ float vlT[64][17], vsT[64][17], vdT[64][17];
    __shared__ float hsr[64];
    __shared__ float hrow[MAXD][65], nrow[MAXD][65];
    __shared__ float eh[16][48], ah[16][48];
    __shared__ float es_s[16];
    __shared__ int dlist[MAXD];
    __shared__ int wbase[8];
    __shared__ int nnz_s;
    __shared__ float part[8][64];

    for (int idx = t; idx < 1024; idx += 512) {
        int i = idx & 63, hd = idx >> 6;
        vlT[i][hd] = ve1[hd * 64 + i];
        vsT[i][hd] = vs1[hd * 64 + i];
        vdT[i][hd] = vd1[hd * 64 + i];
    }
    if (t < 64) hsr[t] = h[s * 64 + t];
    float a = adj[s * 512 + t];
    unsigned long long mask = __ballot(a > 0.f);
    if (l == 0) wbase[w] = __popcll(mask);
    __syncthreads();
    if (t == 0) {
        int run = 0;
        #pragma unroll
        for (int i = 0; i < 8; i++) { int c = wbase[i]; wbase[i] = run; run += c; }
        nnz_s = run;
    }
    __syncthreads();
    if (a > 0.f) {
        int slot = wbase[w] + __popcll(mask & ((1ULL << l) - 1ULL));
        if (slot < MAXD) dlist[slot] = t;
    }
    __syncthreads();
    int nnz = min(nnz_s, MAXD);

    if (nnz == 0) {
        int i = t & 63, q = t >> 6;
        float acc = 0.f;
        for (int d = q * 64; d < q * 64 + 64; d++) acc += h[d * 64 + i];
        part[q][i] = acc;
        __syncthreads();
        if (t < 64) {
            float sum = 0.f;
            #pragma unroll
            for (int q2 = 0; q2 < 8; q2++) sum += part[q2][t];
            float v = sum * (1.f / 512.f);
            for (int hd = 0; hd < 16; hd++) z[(size_t)s * 1024 + hd * 64 + t] = v;
        }
        return;
    }

    for (int base = 0; base < nnz; base += 8) {
        int j = base + (t >> 6);
        if (j < nnz) {
            int d = dlist[j];
            hrow[j][l] = h[d * 64 + l];
            nrow[j][l] = n2n[((size_t)s * 512 + d) * 64 + l];
        }
    }
    if (t < 16) {   // es[hd] = h[s]·vs1[hd]
        float acc = 0.f;
        for (int i = 0; i < 64; i++) acc += hsr[i] * vsT[i][t];
        es_s[t] = acc;
    }
    __syncthreads();
    // logits: e[hd][j] = lrelu(es + hrow[j]·vd1[hd] + nrow[j]·ve1[hd])
    for (int jb = 0; jb < nnz; jb += 32) {
        int j = jb + (t >> 4), hd = t & 15;
        if (j < nnz) {
            float ee = 0.f, edv = 0.f;
            #pragma unroll 8
            for (int i = 0; i < 64; i++) {
                ee  += nrow[j][i] * vlT[i][hd];
                edv += hrow[j][i] * vdT[i][hd];
            }
            eh[hd][j] = lrelu(es_s[hd] + edv + ee);
        }
    }
    __syncthreads();
    {
        int hd = t >> 5, lane32 = t & 31;
        float v0 = (lane32 < nnz) ? eh[hd][lane32] : -1e30f;
        float v1 = (lane32 + 32 < nnz) ? eh[hd][lane32 + 32] : -1e30f;
        float m = half_max(fmaxf(v0, v1));
        float p0 = (lane32 < nnz) ? expf(v0 - m) : 0.f;
        float p1 = (lane32 + 32 < nnz) ? expf(v1 - m) : 0.f;
        float Z = half_sum(p0 + p1);
        float inv = 1.f / Z;
        if (lane32 < nnz) ah[hd][lane32] = p0 * inv;
        if (lane32 + 32 < nnz) ah[hd][lane32 + 32] = p1 * inv;
    }
    __syncthreads();
    int hd = t >> 5, i0 = t & 31;
    float a0 = 0.f, a1 = 0.f;
    for (int j = 0; j < nnz; j++) {
        float aj = ah[hd][j];
        a0 += aj * hrow[j][i0];
        a1 += aj * hrow[j][i0 + 32];
    }
    z[(size_t)s * 1024 + hd * 64 + i0]      = a0;
    z[(size_t)s * 1024 + hd * 64 + i0 + 32] = a1;
}

// ---------------- K_big2p: hout(z@Wg) + pool1 + gate2 + wh2 fused [R17-proven] ----------------
// grid 128, block 1024
__global__ void k_big2p(const float* __restrict__ z, const float* __restrict__ Wg,
                        const float* __restrict__ Wp1, const float* __restrict__ bp1,
                        const float* __restrict__ g2W, const float* __restrict__ g2b,
                        const float* __restrict__ Wo,
                        const float* __restrict__ aos, const float* __restrict__ aod,
                        float* __restrict__ x1p, float* __restrict__ gate2,
                        float* __restrict__ Wh2, float* __restrict__ es2, float* __restrict__ ed2) {
    int b = blockIdx.x, t = threadIdx.x;
    __shared__ __align__(16) char smem[57600];
    float (*zt)[1024]    = reinterpret_cast<float(*)[1024]>(smem);
    float (*xr)[2048]    = reinterpret_cast<float(*)[2048]>(smem);
    float (*hs)[2048]    = reinterpret_cast<float(*)[2048]>(smem + 16384);
    float (*part)[2][128]= reinterpret_cast<float(*)[2][128]>(smem + 49152);
    float *red = reinterpret_cast<float*>(smem + 57344);
    float *rs  = reinterpret_cast<float*>(smem + 57408);
    float *rd  = reinterpret_cast<float*>(smem + 57424);
    int n0 = 2 * b;
    for (int idx = t; idx < 4096; idx += 1024)
        zt[idx >> 10][idx & 1023] = z[(size_t)(4 * b) * 1024 + idx];
    __syncthreads();
    {
        int c = t & 127, g8 = t >> 7;
        #pragma unroll
        for (int it = 0; it < 2; it++) {
            int hd = g8 + 8 * it;
            const float* W = Wg + (size_t)hd * 8192 + c;
            const float* z0 = &zt[0][hd * 64];
            const float* z1 = &zt[1][hd * 64];
            const float* z2 = &zt[2][hd * 64];
            const float* z3 = &zt[3][hd * 64];
            float a0 = 0.f, a1 = 0.f, a2 = 0.f, a3 = 0.f;
            #pragma unroll 8
            for (int i = 0; i < 64; i++) {
                float wv = W[(size_t)i * 128];
                a0 += z0[i] * wv; a1 += z1[i] * wv;
                a2 += z2[i] * wv; a3 += z3[i] * wv;
            }
            hs[0][hd * 128 + c] = eluf(a0);
            hs[1][hd * 128 + c] = eluf(a1);
            hs[2][hd * 128 + c] = eluf(a2);
            hs[3][hd * 128 + c] = eluf(a3);
        }
    }
    __syncthreads();
    int g = t >> 9, tt = t & 511;
    float p = 0.f;
    for (int f = tt; f < 2048; f += 512)
        p += hs[2 * g][f] * Wp1[f] + hs[2 * g + 1][f] * Wp1[2048 + f];
    p = wave_sum(p);
    if ((t & 63) == 0) red[t >> 6] = p;
    __syncthreads();
    float s8 = 0.f;
    #pragma unroll
    for (int k2 = 0; k2 < 8; k2++) s8 += red[g * 8 + k2];
    float sc = sigm(s8 + bp1[0]);
    __syncthreads();
    float pg = 0.f;
    for (int f = tt; f < 2048; f += 512) {
        float v = (hs[2 * g][f] + hs[2 * g + 1][f]) * sc;
        xr[g][f] = v;
        x1p[(size_t)(n0 + g) * 2048 + f] = v;
        pg += v * g2W[f];
    }
    pg = wave_sum(pg);
    if ((t & 63) == 0) red[t >> 6] = pg;
    __syncthreads();
    if (t == 0 || t == 512) {
        float sg8 = 0.f;
        #pragma unroll
        for (int k2 = 0; k2 < 8; k2++) sg8 += red[g * 8 + k2];
        gate2[n0 + g] = sigm(sg8 + g2b[0]);
    }
    int ks = t >> 7, c = t & 127;
    float a0 = 0.f, a1 = 0.f;
    const float* W  = Wo + (size_t)(ks * 256) * 128 + c;
    const float* x0 = xr[0] + ks * 256;
    const float* x1 = xr[1] + ks * 256;
    #pragma unroll 8
    for (int i = 0; i < 256; i++) { float w = W[(size_t)i * 128]; a0 += x0[i] * w; a1 += x1[i] * w; }
    part[ks][0][c] = a0;
    part[ks][1][c] = a1;
    __syncthreads();
    if (t < 256) {
        int r = t >> 7, cc = t & 127;
        float a = 0.f;
        #pragma unroll
        for (int k2 = 0; k2 < 8; k2++) a += part[k2][r][cc];
        Wh2[(n0 + r) * 128 + cc] = a;
        float ps = wave_sum(a * aos[cc]);
        float pd = wave_sum(a * aod[cc]);
        if ((t & 63) == 0) { rs[t >> 6] = ps; rd[t >> 6] = pd; }
    }
    __syncthreads();
    if (t == 0) { es2[n0] = rs[0] + rs[1]; ed2[n0] = rd[0] + rd[1]; }
    if (t == 1) { es2[n0 + 1] = rs[2] + rs[3]; ed2[n0 + 1] = rd[2] + rd[3]; }
}

// ---------------- K_fin: attn2 (b 0..255) | wsum2p (b 256..319) [R15-proven] ----------------
// grid 320, block 256
__global__ void k_fin(const int* __restrict__ winner, const float* __restrict__ d2,
                      const float* __restrict__ es2, const float* __restrict__ ed2,
                      const float* __restrict__ Wh2, const float* __restrict__ gate2,
                      const float* __restrict__ x1p,
                      float* __restrict__ part2, float* __restrict__ hout2) {
    int b = blockIdx.x, t = threadIdx.x;
    if (b < 256) {
        int s = b, w = t >> 6, l = t & 63;
        __shared__ float mx[4], sm[4], at[256], part[2][128];
        int win = winner[s * 256 + t];
        float e;
        if (win >= 0) e = lrelu(es2[s] + ed2[t] + d2[win]);
        else e = NEGF;
        float m = wave_max(e);
        if (l == 0) mx[w] = m;
        __syncthreads();
        m = fmaxf(fmaxf(mx[0], mx[1]), fmaxf(mx[2], mx[3]));
        float p = expf(e - m);
        float Z = wave_sum(p);
        if (l == 0) sm[w] = Z;
        __syncthreads();
        Z = sm[0] + sm[1] + sm[2] + sm[3];
        at[t] = p / Z;
        __syncthreads();
        int c = t & 127, hf = t >> 7;
        float acc = 0.f;
        for (int d = hf * 128; d < hf * 128 + 128; d++)
            acc += at[d] * Wh2[d * 128 + c];
        part[hf][c] = acc;
        __syncthreads();
        if (t < 128) hout2[s * 128 + t] = part[0][t] + part[1][t];   // concat=False: no elu
    } else {
        int tile = b - 256;
        int cb = tile >> 3, nb = tile & 7;
        __shared__ float mx2[4], sm2[4], al[256];
        int w = t >> 6, l = t & 63;
        float g = gate2[t];
        float m = wave_max(g);
        if (l == 0) mx2[w] = m;
        __syncthreads();
        m = fmaxf(fmaxf(mx2[0], mx2[1]), fmaxf(mx2[2], mx2[3]));
        float p = expf(g - m);
        float Z = wave_sum(p);
        if (l == 0) sm2[w] = Z;
        __syncthreads();
        Z = sm2[0] + sm2[1] + sm2[2] + sm2[3];
        al[t] = p / Z;
        __syncthreads();
        int c = cb * 256 + t;
        int n0 = nb * 32;
        float acc = 0.f;
        #pragma unroll 8
        for (int n = n0; n < n0 + 32; n++) acc += al[n] * x1p[(size_t)n * 2048 + c];
        part2[nb * 2048 + c] = acc;
    }
}

// ---------------- K_tail: pool2+gate3+gattn3 (b 0) | wsumr (b 1..9) [R15-proven] ----------------
// grid 10, block 512
__global__ void k_tail(const float* __restrict__ hout2, const float* __restrict__ Wp,
                       const float* __restrict__ bp, const float* __restrict__ g3W,
                       const float* __restrict__ g3b, const float* __restrict__ part1,
                       const float* __restrict__ part2, float* __restrict__ out) {
    int t = threadIdx.x, w = t >> 6, l = t & 63;
    if (blockIdx.x > 0) {
        int rb = blockIdx.x - 1;
        if (rb == 0) {
            if (t < 64) {
                float o = 0.f;
                #pragma unroll
                for (int nb = 0; nb < 8; nb++) o += part1[nb * 64 + t];
                out[t] = o;
            }
        } else if (t < 256) {
            int c = (rb - 1) * 256 + t;
            float o = 0.f;
            #pragma unroll
            for (int nb = 0; nb < 8; nb++) o += part2[nb * 2048 + c];
            out[64 + c] = o;
        }
        return;
    }
    __shared__ float x2s[128][129];
    __shared__ float gt[128];
    __shared__ float mx[2], sm[2], al[128], part[4][128];
    float bpv = bp[0], g3bv = g3b[0];
    for (int rr = 0; rr < 16; rr++) {
        int k = w * 16 + rr;
        float a0  = hout2[(size_t)(2 * k) * 128 + l];
        float a0b = hout2[(size_t)(2 * k) * 128 + 64 + l];
        float a1  = hout2[(size_t)(2 * k + 1) * 128 + l];
        float a1b = hout2[(size_t)(2 * k + 1) * 128 + 64 + l];
        float p = a0 * Wp[l] + a0b * Wp[64 + l] + a1 * Wp[128 + l] + a1b * Wp[192 + l];
        p = wave_sum(p);
        float sc = sigm(p + bpv);
        float v  = (a0 + a1) * sc;
        float vb = (a0b + a1b) * sc;
        x2s[k][l] = v;
        x2s[k][64 + l] = vb;
        float g = wave_sum(v * g3W[l] + vb * g3W[64 + l]);
        if (l == 0) gt[k] = sigm(g + g3bv);
    }
    __syncthreads();
    if (t < 128) {
        float g = gt[t];
        float m = wave_max(g);
        if (l == 0) mx[w] = m;
    }
    __syncthreads();
    if (t < 128) {
        float g = gt[t];
        float m = fmaxf(mx[0], mx[1]);
        float p = expf(g - m);
        float Z = wave_sum(p);
        if (l == 0) sm[w] = Z;
        al[t] = p;
    }
    __syncthreads();
    float invZ = 1.f / (sm[0] + sm[1]);
    int q = t >> 7, c = t & 127;
    float acc = 0.f;
    for (int n = q * 32; n < q * 32 + 32; n++) acc += al[n] * x2s[n][c];
    part[q][c] = acc * invZ;
    __syncthreads();
    if (t < 128) out[2112 + t] = part[0][t] + part[1][t] + part[2][t] + part[3][t];
}

extern "C" void kernel_launch(void* const* d_in, const int* in_sizes, int n_in,
                              void* d_out, int out_size, void* d_ws, size_t ws_size,
                              hipStream_t stream) {
    const float* feat  = (const float*)d_in[0];
    const int*   eidx  = (const int*)d_in[1];
    const float* eattr = (const float*)d_in[2];
    const float* adj   = (const float*)d_in[3];
    const float* n2n   = (const float*)d_in[4];
    const float* Wsn   = (const float*)d_in[5];
    const float* asn   = (const float*)d_in[6];
    const float* Wg    = (const float*)d_in[7];
    const float* Weg   = (const float*)d_in[8];
    const float* asrc  = (const float*)d_in[9];
    const float* adst  = (const float*)d_in[10];
    const float* aedge = (const float*)d_in[11];
    const float* Wp1   = (const float*)d_in[12];
    const float* bp1   = (const float*)d_in[13];
    const float* Wo    = (const float*)d_in[14];
    const float* Weo   = (const float*)d_in[15];
    const float* aos   = (const float*)d_in[16];
    const float* aod   = (const float*)d_in[17];
    const float* aoe   = (const float*)d_in[18];
    const float* Wp2   = (const float*)d_in[19];
    const float* bp2   = (const float*)d_in[20];
    const float* g1W   = (const float*)d_in[21];
    const float* g1b   = (const float*)d_in[22];
    const float* g2W   = (const float*)d_in[23];
    const float* g2b   = (const float*)d_in[24];
    const float* g3W   = (const float*)d_in[25];
    const float* g3b   = (const float*)d_in[26];
    float* out = (float*)d_out;

    char* ws = (char*)d_ws;
    float* h      = (float*)(ws + 0x0000000);   // 128KB
    float* z      = (float*)(ws + 0x0020000);   // 2MB
    float* ve1    = (float*)(ws + 0x0430000);   // 4KB
    float* ve2    = (float*)(ws + 0x0431000);   // 8KB
    float* gate1  = (float*)(ws + 0x0433000);   // 2KB
    float* gate2  = (float*)(ws + 0x0434000);   // 1KB
    float* vs1    = (float*)(ws + 0x0436000);   // 4KB
    float* vd1    = (float*)(ws + 0x0438000);   // 4KB
    float* d2     = (float*)(ws + 0x1840000);   // 16KB
    float* x1p    = (float*)(ws + 0x1850000);   // 2MB
    int*   winner = (int*)  (ws + 0x1A50000);   // 256KB
    float* Wh2    = (float*)(ws + 0x1A90000);   // 128KB
    float* es2    = (float*)(ws + 0x1AB0000);   // 1KB
    float* ed2    = (float*)(ws + 0x1AB1000);   // 1KB
    float* hout2  = (float*)(ws + 0x1AB2000);   // 128KB
    float* part2  = (float*)(ws + 0x1AE2000);   // 64KB
    float* part1  = (float*)(ws + 0x1AF2000);   // 2KB

    k_setup  <<<176, 256, 0, stream>>>(Wg, Weg, asrc, adst, aedge, Weo, aoe,
                                       feat, Wsn, asn, g1W, g1b,
                                       vs1, vd1, ve1, ve2, winner, h, gate1);
    k_attn_ze<<<1040, 512, 0, stream>>>(adj, n2n, h, ve1, vs1, vd1, eattr, Weg, ve2,
                                        gate1, eidx, z, d2, part1, winner);
    k_big2p  <<<128, 1024, 0, stream>>>(z, Wg, Wp1, bp1, g2W, g2b, Wo, aos, aod,
                                        x1p, gate2, Wh2, es2, ed2);
    k_fin    <<<320, 256, 0, stream>>>(winner, d2, es2, ed2, Wh2, gate2, x1p, part2, hout2);
    k_tail   <<<10, 512, 0, stream>>>(hout2, Wp2, bp2, g3W, g3b, part1, part2, out);
}